// Round 2
// baseline (2263.498 us; speedup 1.0000x reference)
//
#include <hip/hip_runtime.h>
#include <hip/hip_bf16.h>

typedef unsigned short u16;

__device__ __forceinline__ float bf2f(u16 u) {
    return __uint_as_float(((unsigned)u) << 16);
}
__device__ __forceinline__ u16 f2bf(float f) {
    unsigned u = __float_as_uint(f);
    unsigned r = (u + 0x7fffu + ((u >> 16) & 1u)) >> 16;  // RNE
    return (u16)r;
}

// ---------------- degree + dinv ----------------
__global__ __launch_bounds__(256) void degree_kernel(const int* __restrict__ cols,
                                                     unsigned* __restrict__ deg, int E) {
    int tid = blockIdx.x * 256 + threadIdx.x;
    if (tid < E) atomicAdd(&deg[cols[tid]], 1u);
}

__global__ __launch_bounds__(256) void dinv_kernel(const unsigned* __restrict__ deg,
                                                   float* __restrict__ dinv, int N) {
    int tid = blockIdx.x * 256 + threadIdx.x;
    if (tid < N) dinv[tid] = rsqrtf((float)deg[tid] + 1.0f);  // +1 self loop
}

// ---------------- fp32 GEMM: OutH[i,:] = (X[i,:] @ W) * dinv[i], bf16 out ----------
// 64 rows per block, 256 threads; thread = 4 rows x (NOUT/16) cols register tile.
// X staged in LDS (fp32); W read through L1/L2 (tiny, broadcast-friendly).
template <int NOUT, bool IN_BF16>
__global__ __launch_bounds__(256) void gemm_scale(const void* __restrict__ Xv,
                                                  const float* __restrict__ W,
                                                  const float* __restrict__ dinv,
                                                  u16* __restrict__ OutH, int nrows) {
    constexpr int LDK = 132;  // 128 + 4 fp32 pad
    constexpr int CPT = NOUT / 16;  // cols per thread (8 or 4)
    __shared__ float sX[64 * LDK];

    const int t = threadIdx.x;
    const int row0 = blockIdx.x * 64;

    if (IN_BF16) {
        const u16* X = (const u16*)Xv;
        for (int idx = t; idx < 64 * 16; idx += 256) {  // 16B = 8 bf16 per chunk
            int r = idx >> 4, c = idx & 15;
            int gr = row0 + r;
            float f[8];
            if (gr < nrows) {
                uint4 v = ((const uint4*)X)[(size_t)gr * 16 + c];
                unsigned w[4] = {v.x, v.y, v.z, v.w};
#pragma unroll
                for (int j = 0; j < 4; j++) {
                    f[2 * j]     = __uint_as_float(w[j] << 16);
                    f[2 * j + 1] = __uint_as_float(w[j] & 0xffff0000u);
                }
            } else {
#pragma unroll
                for (int j = 0; j < 8; j++) f[j] = 0.f;
            }
#pragma unroll
            for (int j = 0; j < 8; j++) sX[r * LDK + c * 8 + j] = f[j];
        }
    } else {
        const float* X = (const float*)Xv;
        for (int idx = t; idx < 64 * 32; idx += 256) {  // 16B = 4 fp32 per chunk
            int r = idx >> 5, c = idx & 31;
            int gr = row0 + r;
            float4 v = make_float4(0.f, 0.f, 0.f, 0.f);
            if (gr < nrows) v = ((const float4*)X)[(size_t)gr * 32 + c];
            *((float4*)&sX[r * LDK + c * 4]) = v;
        }
    }
    __syncthreads();

    const int cg = t & 15, rg = t >> 4;
    const int j0 = cg * CPT;
    float acc[4][CPT];
#pragma unroll
    for (int i = 0; i < 4; i++)
#pragma unroll
        for (int j = 0; j < CPT; j++) acc[i][j] = 0.f;

#pragma unroll 4
    for (int k = 0; k < 128; k++) {
        float a[4];
#pragma unroll
        for (int i = 0; i < 4; i++) a[i] = sX[(rg * 4 + i) * LDK + k];
        float b[CPT];
        const float4* wp = (const float4*)(W + (size_t)k * NOUT + j0);
#pragma unroll
        for (int j4 = 0; j4 < CPT / 4; j4++) {
            float4 bv = wp[j4];
            b[j4 * 4 + 0] = bv.x; b[j4 * 4 + 1] = bv.y;
            b[j4 * 4 + 2] = bv.z; b[j4 * 4 + 3] = bv.w;
        }
#pragma unroll
        for (int i = 0; i < 4; i++)
#pragma unroll
            for (int j = 0; j < CPT; j++) acc[i][j] = fmaf(a[i], b[j], acc[i][j]);
    }

#pragma unroll
    for (int i = 0; i < 4; i++) {
        int gi = row0 + rg * 4 + i;
        if (gi < nrows) {
            float dv = dinv[gi];
            u16 pk[CPT];
#pragma unroll
            for (int j = 0; j < CPT; j++) pk[j] = f2bf(acc[i][j] * dv);
            if (CPT == 8) {
                uint4 o;
                o.x = pk[0] | ((unsigned)pk[1] << 16);
                o.y = pk[2] | ((unsigned)pk[3] << 16);
                o.z = pk[4] | ((unsigned)pk[5] << 16);
                o.w = pk[6] | ((unsigned)pk[7] << 16);
                *((uint4*)&OutH[(size_t)gi * NOUT + j0]) = o;
            } else {
                uint2 o;
                o.x = pk[0] | ((unsigned)pk[1] << 16);
                o.y = pk[2] | ((unsigned)pk[3] << 16);
                *((uint2*)&OutH[(size_t)gi * NOUT + j0]) = o;
            }
        }
    }
}

// ---------------- edge scatter: acc[col] += h'[row]  (fp32 atomics) ----------------
template <int NH>  // NH/2 threads per edge, 2 bf16 gathered, 2 fp32 atomics
__global__ __launch_bounds__(256) void scatter_add(const int* __restrict__ rows,
                                                   const int* __restrict__ cols,
                                                   const u16* __restrict__ hs,
                                                   float* __restrict__ acc, int E) {
    constexpr int TPE = NH / 2;
    unsigned tid = blockIdx.x * 256u + threadIdx.x;
    unsigned e = tid / TPE;
    unsigned l = tid % TPE;
    if (e >= (unsigned)E) return;
    int r = rows[e], c = cols[e];
    unsigned v = ((const unsigned*)hs)[(size_t)r * TPE + l];  // 2 bf16
    float f0 = __uint_as_float(v << 16);
    float f1 = __uint_as_float(v & 0xffff0000u);
    atomicAdd(&acc[(size_t)c * NH + 2 * l], f0);
    atomicAdd(&acc[(size_t)c * NH + 2 * l + 1], f1);
}

// ---------------- finalize: out = [relu](dinv[i]*(acc + h'[i]) + b) ----------------
template <int NH, bool RELU, bool OUT_BF16>
__global__ __launch_bounds__(256) void finalize_kernel(const float* __restrict__ acc,
                                                       const u16* __restrict__ hs,
                                                       const float* __restrict__ dinv,
                                                       const float* __restrict__ bias,
                                                       void* __restrict__ outv, int total) {
    int tid = blockIdx.x * 256 + threadIdx.x;
    if (tid >= total) return;
    constexpr int SH = (NH == 128) ? 7 : 6;
    int i = tid >> SH;
    int k = tid & (NH - 1);
    float v = dinv[i] * (acc[tid] + bf2f(hs[tid])) + bias[k];
    if (RELU) v = fmaxf(v, 0.f);
    if (OUT_BF16) ((u16*)outv)[tid] = f2bf(v);
    else          ((float*)outv)[tid] = v;
}

extern "C" void kernel_launch(void* const* d_in, const int* in_sizes, int n_in,
                              void* d_out, int out_size, void* d_ws, size_t ws_size,
                              hipStream_t stream) {
    const float* x  = (const float*)d_in[0];
    const int*   ei = (const int*)d_in[1];
    const float* W1 = (const float*)d_in[2];
    const float* b1 = (const float*)d_in[3];
    const float* W2 = (const float*)d_in[4];
    const float* b2 = (const float*)d_in[5];

    const int N = in_sizes[0] / 128;
    const int E = in_sizes[1] / 2;
    const int* rows = ei;
    const int* cols = ei + E;

    // workspace layout (peak ~103 MB)
    char* ws = (char*)d_ws;
    size_t off = 0;
    auto alloc = [&](size_t bytes) -> void* {
        void* p = ws + off;
        off = (off + bytes + 1023) & ~(size_t)1023;
        return p;
    };
    unsigned* deg  = (unsigned*)alloc((size_t)N * 4);
    float*    dinv = (float*)alloc((size_t)N * 4);
    u16*      h1s  = (u16*)alloc((size_t)N * 128 * 2);   // scaled h', layer 1 (bf16)
    float*    accA = (float*)alloc((size_t)N * 128 * 4); // acc1; later acc2
    u16*      h1b  = (u16*)alloc((size_t)N * 128 * 2);   // relu'd layer-1 output (bf16)
    u16*      h2s  = h1s;                                // reuse after finalize1
    float*    acc2 = accA;                               // reuse after finalize1

    hipMemsetAsync(deg, 0, (size_t)N * 4, stream);
    hipMemsetAsync(accA, 0, (size_t)N * 128 * 4, stream);

    degree_kernel<<<(E + 255) / 256, 256, 0, stream>>>(cols, deg, E);
    dinv_kernel<<<(N + 255) / 256, 256, 0, stream>>>(deg, dinv, N);

    // layer 1
    gemm_scale<128, false><<<(N + 63) / 64, 256, 0, stream>>>(x, W1, dinv, h1s, N);
    {
        size_t threads = (size_t)E * 64;
        scatter_add<128><<<(unsigned)((threads + 255) / 256), 256, 0, stream>>>(rows, cols, h1s, accA, E);
    }
    finalize_kernel<128, true, true><<<(N * 128 + 255) / 256, 256, 0, stream>>>(accA, h1s, dinv, b1, h1b, N * 128);

    // layer 2 (acc2/h2s overlay accA/h1s — safe: stream-ordered after finalize1)
    hipMemsetAsync(acc2, 0, (size_t)N * 64 * 4, stream);
    gemm_scale<64, true><<<(N + 63) / 64, 256, 0, stream>>>(h1b, W2, dinv, h2s, N);
    {
        size_t threads = (size_t)E * 32;
        scatter_add<64><<<(unsigned)((threads + 255) / 256), 256, 0, stream>>>(rows, cols, h2s, acc2, E);
    }
    finalize_kernel<64, false, false><<<(N * 64 + 255) / 256, 256, 0, stream>>>(acc2, h2s, dinv, b2, d_out, N * 64);
}

// Round 3
// 603.184 us; speedup vs baseline: 3.7526x; 3.7526x over previous
//
#include <hip/hip_runtime.h>
#include <hip/hip_bf16.h>

typedef unsigned short u16;

__device__ __forceinline__ float bflo(unsigned u) { return __uint_as_float(u << 16); }
__device__ __forceinline__ float bfhi(unsigned u) { return __uint_as_float(u & 0xffff0000u); }
__device__ __forceinline__ u16 f2bf(float f) {
    unsigned u = __float_as_uint(f);
    return (u16)((u + 0x7fffu + ((u >> 16) & 1u)) >> 16);  // RNE
}

// ---------------- degree + dinv ----------------
__global__ __launch_bounds__(256) void degree_kernel(const int* __restrict__ cols,
                                                     unsigned* __restrict__ deg, int E) {
    int tid = blockIdx.x * 256 + threadIdx.x;
    if (tid < E) atomicAdd(&deg[cols[tid]], 1u);
}

__global__ __launch_bounds__(256) void dinv_kernel(const unsigned* __restrict__ deg,
                                                   float* __restrict__ dinv, int N) {
    int tid = blockIdx.x * 256 + threadIdx.x;
    if (tid < N) dinv[tid] = rsqrtf((float)deg[tid] + 1.0f);  // +1 self loop
}

// ---------------- exclusive scan of deg -> rowptr (3 kernels) ----------------
__global__ __launch_bounds__(256) void scan_blocks(const unsigned* __restrict__ deg,
                                                   int* __restrict__ rowptr,
                                                   unsigned* __restrict__ partials, int N) {
    __shared__ unsigned s[256];
    int t = threadIdx.x;
    int gid = blockIdx.x * 256 + t;
    unsigned val = (gid < N) ? deg[gid] : 0u;
    s[t] = val;
    __syncthreads();
#pragma unroll
    for (int off = 1; off < 256; off <<= 1) {
        unsigned v = (t >= off) ? s[t - off] : 0u;
        __syncthreads();
        s[t] += v;
        __syncthreads();
    }
    if (gid < N) rowptr[gid] = (int)(s[t] - val);  // exclusive within block
    if (t == 255) partials[blockIdx.x] = s[255];
}

__global__ __launch_bounds__(512) void scan_partials(unsigned* __restrict__ partials, int NB) {
    __shared__ unsigned s[512];
    int t = threadIdx.x;
    unsigned val = (t < NB) ? partials[t] : 0u;
    s[t] = val;
    __syncthreads();
#pragma unroll
    for (int off = 1; off < 512; off <<= 1) {
        unsigned v = (t >= off) ? s[t - off] : 0u;
        __syncthreads();
        s[t] += v;
        __syncthreads();
    }
    if (t < NB) partials[t] = s[t] - val;  // exclusive
}

__global__ __launch_bounds__(256) void add_base(int* __restrict__ rowptr,
                                                const unsigned* __restrict__ partials,
                                                int N, int E) {
    int tid = blockIdx.x * 256 + threadIdx.x;
    if (tid < N) rowptr[tid] += (int)partials[tid >> 8];
    if (tid == 0) rowptr[N] = E;
}

// ---------------- bucket fill: srcidx sorted by destination ----------------
__global__ __launch_bounds__(256) void fill_kernel(const int* __restrict__ rows,
                                                   const int* __restrict__ cols,
                                                   const int* __restrict__ rowptr,
                                                   unsigned* __restrict__ cur,
                                                   int* __restrict__ srcidx, int E) {
    int tid = blockIdx.x * 256 + threadIdx.x;
    if (tid >= E) return;
    int c = cols[tid];
    int slot = rowptr[c] + (int)atomicAdd(&cur[c], 1u);
    srcidx[slot] = rows[tid];
}

// ---------------- fp32 GEMM: OutH[i,:] = (X[i,:] @ W) * dinv[i], bf16 out ----------
template <int NOUT, bool IN_BF16>
__global__ __launch_bounds__(256) void gemm_scale(const void* __restrict__ Xv,
                                                  const float* __restrict__ W,
                                                  const float* __restrict__ dinv,
                                                  u16* __restrict__ OutH, int nrows) {
    constexpr int LDK = 132;
    constexpr int CPT = NOUT / 16;
    __shared__ float sX[64 * LDK];

    const int t = threadIdx.x;
    const int row0 = blockIdx.x * 64;

    if (IN_BF16) {
        const u16* X = (const u16*)Xv;
        for (int idx = t; idx < 64 * 16; idx += 256) {
            int r = idx >> 4, c = idx & 15;
            int gr = row0 + r;
            float f[8];
            if (gr < nrows) {
                uint4 v = ((const uint4*)X)[(size_t)gr * 16 + c];
                unsigned w[4] = {v.x, v.y, v.z, v.w};
#pragma unroll
                for (int j = 0; j < 4; j++) {
                    f[2 * j] = bflo(w[j]);
                    f[2 * j + 1] = bfhi(w[j]);
                }
            } else {
#pragma unroll
                for (int j = 0; j < 8; j++) f[j] = 0.f;
            }
#pragma unroll
            for (int j = 0; j < 8; j++) sX[r * LDK + c * 8 + j] = f[j];
        }
    } else {
        const float* X = (const float*)Xv;
        for (int idx = t; idx < 64 * 32; idx += 256) {
            int r = idx >> 5, c = idx & 31;
            int gr = row0 + r;
            float4 v = make_float4(0.f, 0.f, 0.f, 0.f);
            if (gr < nrows) v = ((const float4*)X)[(size_t)gr * 32 + c];
            *((float4*)&sX[r * LDK + c * 4]) = v;
        }
    }
    __syncthreads();

    const int cg = t & 15, rg = t >> 4;
    const int j0 = cg * CPT;
    float acc[4][CPT];
#pragma unroll
    for (int i = 0; i < 4; i++)
#pragma unroll
        for (int j = 0; j < CPT; j++) acc[i][j] = 0.f;

#pragma unroll 4
    for (int k = 0; k < 128; k++) {
        float a[4];
#pragma unroll
        for (int i = 0; i < 4; i++) a[i] = sX[(rg * 4 + i) * LDK + k];
        float b[CPT];
        const float4* wp = (const float4*)(W + (size_t)k * NOUT + j0);
#pragma unroll
        for (int j4 = 0; j4 < CPT / 4; j4++) {
            float4 bv = wp[j4];
            b[j4 * 4 + 0] = bv.x; b[j4 * 4 + 1] = bv.y;
            b[j4 * 4 + 2] = bv.z; b[j4 * 4 + 3] = bv.w;
        }
#pragma unroll
        for (int i = 0; i < 4; i++)
#pragma unroll
            for (int j = 0; j < CPT; j++) acc[i][j] = fmaf(a[i], b[j], acc[i][j]);
    }

#pragma unroll
    for (int i = 0; i < 4; i++) {
        int gi = row0 + rg * 4 + i;
        if (gi < nrows) {
            float dv = dinv[gi];
            u16 pk[CPT];
#pragma unroll
            for (int j = 0; j < CPT; j++) pk[j] = f2bf(acc[i][j] * dv);
            if (CPT == 8) {
                uint4 o;
                o.x = pk[0] | ((unsigned)pk[1] << 16);
                o.y = pk[2] | ((unsigned)pk[3] << 16);
                o.z = pk[4] | ((unsigned)pk[5] << 16);
                o.w = pk[6] | ((unsigned)pk[7] << 16);
                *((uint4*)&OutH[(size_t)gi * NOUT + j0]) = o;
            } else {
                uint2 o;
                o.x = pk[0] | ((unsigned)pk[1] << 16);
                o.y = pk[2] | ((unsigned)pk[3] << 16);
                *((uint2*)&OutH[(size_t)gi * NOUT + j0]) = o;
            }
        }
    }
}

// ---- aggregate+finalize: out[c] = [relu](dinv[c]*(Σ_in h'[r] + h'[c]) + b) ----
// WPN = NH/2 lanes per node, each lane owns 2 features (one u32 of bf16 pair).
template <int NH, bool RELU, bool OUT_BF16>
__global__ __launch_bounds__(256) void aggregate(const int* __restrict__ rowptr,
                                                 const int* __restrict__ srcidx,
                                                 const u16* __restrict__ hs,
                                                 const float* __restrict__ dinv,
                                                 const float* __restrict__ bias,
                                                 void* __restrict__ outv, int N) {
    constexpr int WPN = NH / 2;
    int tid = blockIdx.x * 256 + threadIdx.x;
    int node = tid / WPN;
    int fl = tid % WPN;
    if (node >= N) return;

    const unsigned* h32 = (const unsigned*)hs;
    int start = rowptr[node], end = rowptr[node + 1];

    unsigned v = h32[(size_t)node * WPN + fl];  // self loop h'[c]
    float a0 = bflo(v), a1 = bfhi(v);
    for (int i = start; i < end; ++i) {
        int r = srcidx[i];
        unsigned u = h32[(size_t)r * WPN + fl];
        a0 += bflo(u);
        a1 += bfhi(u);
    }
    float dv = dinv[node];
    float o0 = dv * a0 + bias[2 * fl];
    float o1 = dv * a1 + bias[2 * fl + 1];
    if (RELU) {
        o0 = fmaxf(o0, 0.f);
        o1 = fmaxf(o1, 0.f);
    }
    if (OUT_BF16) {
        ((unsigned*)outv)[tid] = (unsigned)f2bf(o0) | ((unsigned)f2bf(o1) << 16);
    } else {
        ((float2*)outv)[tid] = make_float2(o0, o1);
    }
}

extern "C" void kernel_launch(void* const* d_in, const int* in_sizes, int n_in,
                              void* d_out, int out_size, void* d_ws, size_t ws_size,
                              hipStream_t stream) {
    const float* x  = (const float*)d_in[0];
    const int*   ei = (const int*)d_in[1];
    const float* W1 = (const float*)d_in[2];
    const float* b1 = (const float*)d_in[3];
    const float* W2 = (const float*)d_in[4];
    const float* b2 = (const float*)d_in[5];

    const int N = in_sizes[0] / 128;
    const int E = in_sizes[1] / 2;
    const int* rows = ei;
    const int* cols = ei + E;
    const int NB = (N + 255) / 256;  // scan blocks (must be <= 512)

    char* ws = (char*)d_ws;
    size_t off = 0;
    auto alloc = [&](size_t bytes) -> void* {
        void* p = ws + off;
        off = (off + bytes + 1023) & ~(size_t)1023;
        return p;
    };
    unsigned* deg      = (unsigned*)alloc((size_t)N * 4);
    float*    dinv     = (float*)alloc((size_t)N * 4);
    int*      rowptr   = (int*)alloc((size_t)(N + 1) * 4);
    unsigned* cur      = (unsigned*)alloc((size_t)N * 4);
    unsigned* partials = (unsigned*)alloc(512 * 4);
    int*      srcidx   = (int*)alloc((size_t)E * 4);
    u16*      h1s      = (u16*)alloc((size_t)N * 128 * 2);  // (x@W1)*dinv, bf16
    u16*      h1b      = (u16*)alloc((size_t)N * 128 * 2);  // relu'd layer-1 out, bf16
    u16*      h2s      = h1s;                               // reuse

    hipMemsetAsync(deg, 0, (size_t)N * 4, stream);
    hipMemsetAsync(cur, 0, (size_t)N * 4, stream);

    degree_kernel<<<(E + 255) / 256, 256, 0, stream>>>(cols, deg, E);
    dinv_kernel<<<NB, 256, 0, stream>>>(deg, dinv, N);

    // CSR build (by destination)
    scan_blocks<<<NB, 256, 0, stream>>>(deg, rowptr, partials, N);
    scan_partials<<<1, 512, 0, stream>>>(partials, NB);
    add_base<<<NB, 256, 0, stream>>>(rowptr, partials, N, E);
    fill_kernel<<<(E + 255) / 256, 256, 0, stream>>>(rows, cols, rowptr, cur, srcidx, E);

    // layer 1
    gemm_scale<128, false><<<(N + 63) / 64, 256, 0, stream>>>(x, W1, dinv, h1s, N);
    aggregate<128, true, true><<<(N * 64 + 255) / 256, 256, 0, stream>>>(
        rowptr, srcidx, h1s, dinv, b1, h1b, N);

    // layer 2
    gemm_scale<64, true><<<(N + 63) / 64, 256, 0, stream>>>(h1b, W2, dinv, h2s, N);
    aggregate<64, false, false><<<(N * 32 + 255) / 256, 256, 0, stream>>>(
        rowptr, srcidx, h2s, dinv, b2, d_out, N);
}

// Round 4
// 476.832 us; speedup vs baseline: 4.7470x; 1.2650x over previous
//
#include <hip/hip_runtime.h>
#include <hip/hip_bf16.h>

typedef unsigned short u16;

__device__ __forceinline__ float bflo(unsigned u) { return __uint_as_float(u << 16); }
__device__ __forceinline__ float bfhi(unsigned u) { return __uint_as_float(u & 0xffff0000u); }
__device__ __forceinline__ u16 f2bf(float f) {
    unsigned u = __float_as_uint(f);
    return (u16)((u + 0x7fffu + ((u >> 16) & 1u)) >> 16);  // RNE
}

// ---------------- degree + dinv ----------------
__global__ __launch_bounds__(256) void degree_kernel(const int* __restrict__ cols,
                                                     unsigned* __restrict__ deg, int E) {
    int tid = blockIdx.x * 256 + threadIdx.x;
    if (tid < E) atomicAdd(&deg[cols[tid]], 1u);
}

__global__ __launch_bounds__(256) void dinv_kernel(const unsigned* __restrict__ deg,
                                                   float* __restrict__ dinv, int N) {
    int tid = blockIdx.x * 256 + threadIdx.x;
    if (tid < N) dinv[tid] = rsqrtf((float)deg[tid] + 1.0f);  // +1 self loop
}

// ---------------- exclusive scan of deg -> rowptr (3 kernels) ----------------
__global__ __launch_bounds__(256) void scan_blocks(const unsigned* __restrict__ deg,
                                                   int* __restrict__ rowptr,
                                                   unsigned* __restrict__ partials, int N) {
    __shared__ unsigned s[256];
    int t = threadIdx.x;
    int gid = blockIdx.x * 256 + t;
    unsigned val = (gid < N) ? deg[gid] : 0u;
    s[t] = val;
    __syncthreads();
#pragma unroll
    for (int off = 1; off < 256; off <<= 1) {
        unsigned v = (t >= off) ? s[t - off] : 0u;
        __syncthreads();
        s[t] += v;
        __syncthreads();
    }
    if (gid < N) rowptr[gid] = (int)(s[t] - val);  // exclusive within block
    if (t == 255) partials[blockIdx.x] = s[255];
}

__global__ __launch_bounds__(512) void scan_partials(unsigned* __restrict__ partials, int NB) {
    __shared__ unsigned s[512];
    int t = threadIdx.x;
    unsigned val = (t < NB) ? partials[t] : 0u;
    s[t] = val;
    __syncthreads();
#pragma unroll
    for (int off = 1; off < 512; off <<= 1) {
        unsigned v = (t >= off) ? s[t - off] : 0u;
        __syncthreads();
        s[t] += v;
        __syncthreads();
    }
    if (t < NB) partials[t] = s[t] - val;  // exclusive
}

__global__ __launch_bounds__(256) void add_base(int* __restrict__ rowptr,
                                                const unsigned* __restrict__ partials,
                                                int N, int E) {
    int tid = blockIdx.x * 256 + threadIdx.x;
    if (tid < N) rowptr[tid] += (int)partials[tid >> 8];
    if (tid == 0) rowptr[N] = E;
}

// ---------------- bucket fill: srcidx sorted by destination ----------------
__global__ __launch_bounds__(256) void fill_kernel(const int* __restrict__ rows,
                                                   const int* __restrict__ cols,
                                                   const int* __restrict__ rowptr,
                                                   unsigned* __restrict__ cur,
                                                   int* __restrict__ srcidx, int E) {
    int tid = blockIdx.x * 256 + threadIdx.x;
    if (tid >= E) return;
    int c = cols[tid];
    int slot = rowptr[c] + (int)atomicAdd(&cur[c], 1u);
    srcidx[slot] = rows[tid];
}

// ---------------- fp32 GEMM: OutH[i,:] = (X[i,:] @ W) * dinv[i], bf16 out ----------
template <int NOUT, bool IN_BF16>
__global__ __launch_bounds__(256) void gemm_scale(const void* __restrict__ Xv,
                                                  const float* __restrict__ W,
                                                  const float* __restrict__ dinv,
                                                  u16* __restrict__ OutH, int nrows) {
    constexpr int LDK = 132;
    constexpr int CPT = NOUT / 16;
    __shared__ float sX[64 * LDK];

    const int t = threadIdx.x;
    const int row0 = blockIdx.x * 64;

    if (IN_BF16) {
        const u16* X = (const u16*)Xv;
        for (int idx = t; idx < 64 * 16; idx += 256) {
            int r = idx >> 4, c = idx & 15;
            int gr = row0 + r;
            float f[8];
            if (gr < nrows) {
                uint4 v = ((const uint4*)X)[(size_t)gr * 16 + c];
                unsigned w[4] = {v.x, v.y, v.z, v.w};
#pragma unroll
                for (int j = 0; j < 4; j++) {
                    f[2 * j] = bflo(w[j]);
                    f[2 * j + 1] = bfhi(w[j]);
                }
            } else {
#pragma unroll
                for (int j = 0; j < 8; j++) f[j] = 0.f;
            }
#pragma unroll
            for (int j = 0; j < 8; j++) sX[r * LDK + c * 8 + j] = f[j];
        }
    } else {
        const float* X = (const float*)Xv;
        for (int idx = t; idx < 64 * 32; idx += 256) {
            int r = idx >> 5, c = idx & 31;
            int gr = row0 + r;
            float4 v = make_float4(0.f, 0.f, 0.f, 0.f);
            if (gr < nrows) v = ((const float4*)X)[(size_t)gr * 32 + c];
            *((float4*)&sX[r * LDK + c * 4]) = v;
        }
    }
    __syncthreads();

    const int cg = t & 15, rg = t >> 4;
    const int j0 = cg * CPT;
    float acc[4][CPT];
#pragma unroll
    for (int i = 0; i < 4; i++)
#pragma unroll
        for (int j = 0; j < CPT; j++) acc[i][j] = 0.f;

#pragma unroll 4
    for (int k = 0; k < 128; k++) {
        float a[4];
#pragma unroll
        for (int i = 0; i < 4; i++) a[i] = sX[(rg * 4 + i) * LDK + k];
        float b[CPT];
        const float4* wp = (const float4*)(W + (size_t)k * NOUT + j0);
#pragma unroll
        for (int j4 = 0; j4 < CPT / 4; j4++) {
            float4 bv = wp[j4];
            b[j4 * 4 + 0] = bv.x; b[j4 * 4 + 1] = bv.y;
            b[j4 * 4 + 2] = bv.z; b[j4 * 4 + 3] = bv.w;
        }
#pragma unroll
        for (int i = 0; i < 4; i++)
#pragma unroll
            for (int j = 0; j < CPT; j++) acc[i][j] = fmaf(a[i], b[j], acc[i][j]);
    }

#pragma unroll
    for (int i = 0; i < 4; i++) {
        int gi = row0 + rg * 4 + i;
        if (gi < nrows) {
            float dv = dinv[gi];
            u16 pk[CPT];
#pragma unroll
            for (int j = 0; j < CPT; j++) pk[j] = f2bf(acc[i][j] * dv);
            if (CPT == 8) {
                uint4 o;
                o.x = pk[0] | ((unsigned)pk[1] << 16);
                o.y = pk[2] | ((unsigned)pk[3] << 16);
                o.z = pk[4] | ((unsigned)pk[5] << 16);
                o.w = pk[6] | ((unsigned)pk[7] << 16);
                *((uint4*)&OutH[(size_t)gi * NOUT + j0]) = o;
            } else {
                uint2 o;
                o.x = pk[0] | ((unsigned)pk[1] << 16);
                o.y = pk[2] | ((unsigned)pk[3] << 16);
                *((uint2*)&OutH[(size_t)gi * NOUT + j0]) = o;
            }
        }
    }
}

// ---- aggregate+finalize: out[c] = [relu](dinv[c]*(Σ_in h'[r] + h'[c]) + b) ----
// WPN = NH/4 lanes per node, each lane owns 4 features (uint2 of bf16 pairs).
// Edge loop unrolled 8x: 8 srcidx loads, then 8 independent row-gathers in flight.
template <int NH, bool RELU, bool OUT_BF16>
__global__ __launch_bounds__(256) void aggregate(const int* __restrict__ rowptr,
                                                 const int* __restrict__ srcidx,
                                                 const u16* __restrict__ hs,
                                                 const float* __restrict__ dinv,
                                                 const float* __restrict__ bias,
                                                 void* __restrict__ outv, int N) {
    constexpr int WPN = NH / 4;
    int tid = blockIdx.x * 256 + threadIdx.x;
    int node = tid / WPN;
    int fl = tid % WPN;
    if (node >= N) return;

    const uint2* h64 = (const uint2*)hs;
    int start = rowptr[node], end = rowptr[node + 1];

    uint2 v = h64[(size_t)node * WPN + fl];  // self loop h'[c]
    float a0 = bflo(v.x), a1 = bfhi(v.x), a2 = bflo(v.y), a3 = bfhi(v.y);

    int i = start;
    for (; i + 8 <= end; i += 8) {
        int r[8];
#pragma unroll
        for (int j = 0; j < 8; j++) r[j] = srcidx[i + j];
        uint2 u[8];
#pragma unroll
        for (int j = 0; j < 8; j++) u[j] = h64[(size_t)r[j] * WPN + fl];
#pragma unroll
        for (int j = 0; j < 8; j++) {
            a0 += bflo(u[j].x);
            a1 += bfhi(u[j].x);
            a2 += bflo(u[j].y);
            a3 += bfhi(u[j].y);
        }
    }
    for (; i < end; ++i) {
        int r = srcidx[i];
        uint2 u = h64[(size_t)r * WPN + fl];
        a0 += bflo(u.x);
        a1 += bfhi(u.x);
        a2 += bflo(u.y);
        a3 += bfhi(u.y);
    }

    float dv = dinv[node];
    float4 bv = ((const float4*)bias)[fl];
    float o0 = dv * a0 + bv.x;
    float o1 = dv * a1 + bv.y;
    float o2 = dv * a2 + bv.z;
    float o3 = dv * a3 + bv.w;
    if (RELU) {
        o0 = fmaxf(o0, 0.f);
        o1 = fmaxf(o1, 0.f);
        o2 = fmaxf(o2, 0.f);
        o3 = fmaxf(o3, 0.f);
    }
    if (OUT_BF16) {
        uint2 o;
        o.x = (unsigned)f2bf(o0) | ((unsigned)f2bf(o1) << 16);
        o.y = (unsigned)f2bf(o2) | ((unsigned)f2bf(o3) << 16);
        ((uint2*)outv)[tid] = o;
    } else {
        ((float4*)outv)[tid] = make_float4(o0, o1, o2, o3);
    }
}

extern "C" void kernel_launch(void* const* d_in, const int* in_sizes, int n_in,
                              void* d_out, int out_size, void* d_ws, size_t ws_size,
                              hipStream_t stream) {
    const float* x  = (const float*)d_in[0];
    const int*   ei = (const int*)d_in[1];
    const float* W1 = (const float*)d_in[2];
    const float* b1 = (const float*)d_in[3];
    const float* W2 = (const float*)d_in[4];
    const float* b2 = (const float*)d_in[5];

    const int N = in_sizes[0] / 128;
    const int E = in_sizes[1] / 2;
    const int* rows = ei;
    const int* cols = ei + E;
    const int NB = (N + 255) / 256;  // scan blocks (must be <= 512)

    char* ws = (char*)d_ws;
    size_t off = 0;
    auto alloc = [&](size_t bytes) -> void* {
        void* p = ws + off;
        off = (off + bytes + 1023) & ~(size_t)1023;
        return p;
    };
    unsigned* deg      = (unsigned*)alloc((size_t)N * 4);
    float*    dinv     = (float*)alloc((size_t)N * 4);
    int*      rowptr   = (int*)alloc((size_t)(N + 1) * 4);
    unsigned* cur      = (unsigned*)alloc((size_t)N * 4);
    unsigned* partials = (unsigned*)alloc(512 * 4);
    int*      srcidx   = (int*)alloc((size_t)E * 4);
    u16*      h1s      = (u16*)alloc((size_t)N * 128 * 2);  // (x@W1)*dinv, bf16
    u16*      h1b      = (u16*)alloc((size_t)N * 128 * 2);  // relu'd layer-1 out, bf16
    u16*      h2s      = h1s;                               // reuse

    hipMemsetAsync(deg, 0, (size_t)N * 4, stream);
    hipMemsetAsync(cur, 0, (size_t)N * 4, stream);

    degree_kernel<<<(E + 255) / 256, 256, 0, stream>>>(cols, deg, E);
    dinv_kernel<<<NB, 256, 0, stream>>>(deg, dinv, N);

    // CSR build (by destination)
    scan_blocks<<<NB, 256, 0, stream>>>(deg, rowptr, partials, N);
    scan_partials<<<1, 512, 0, stream>>>(partials, NB);
    add_base<<<NB, 256, 0, stream>>>(rowptr, partials, N, E);
    fill_kernel<<<(E + 255) / 256, 256, 0, stream>>>(rows, cols, rowptr, cur, srcidx, E);

    // layer 1
    gemm_scale<128, false><<<(N + 63) / 64, 256, 0, stream>>>(x, W1, dinv, h1s, N);
    aggregate<128, true, true><<<(N * 32 + 255) / 256, 256, 0, stream>>>(
        rowptr, srcidx, h1s, dinv, b1, h1b, N);

    // layer 2
    gemm_scale<64, true><<<(N + 63) / 64, 256, 0, stream>>>(h1b, W2, dinv, h2s, N);
    aggregate<64, false, false><<<(N * 16 + 255) / 256, 256, 0, stream>>>(
        rowptr, srcidx, h2s, dinv, b2, d_out, N);
}

// Round 5
// 410.105 us; speedup vs baseline: 5.5193x; 1.1627x over previous
//
#include <hip/hip_runtime.h>
#include <hip/hip_bf16.h>

typedef unsigned short u16;

__device__ __forceinline__ float bflo(unsigned u) { return __uint_as_float(u << 16); }
__device__ __forceinline__ float bfhi(unsigned u) { return __uint_as_float(u & 0xffff0000u); }
__device__ __forceinline__ u16 f2bf(float f) {
    unsigned u = __float_as_uint(f);
    return (u16)((u + 0x7fffu + ((u >> 16) & 1u)) >> 16);  // RNE
}

#define CHUNK 8192     // edges per block in pass A
#define BN 512         // nodes per bucket (bucket = c >> 9)

// ---- pass A1: per-block bucket histogram ----
__global__ __launch_bounds__(256) void hist_kernel(const int* __restrict__ cols,
                                                   unsigned* __restrict__ hist,
                                                   int E, int nblocksA, int nbuckets) {
    __shared__ unsigned h[256];
    int t = threadIdx.x, blk = blockIdx.x;
    h[t] = 0;
    __syncthreads();
    int base = blk * CHUNK;
#pragma unroll
    for (int j = 0; j < CHUNK / 256; j++) {
        int i = base + j * 256 + t;
        if (i < E) atomicAdd(&h[((unsigned)cols[i]) >> 9], 1u);
    }
    __syncthreads();
    if (t < nbuckets) hist[t * nblocksA + blk] = h[t];
}

// ---- pass A2: per-bucket block prefixes + bucket bases (single WG) ----
__global__ __launch_bounds__(256) void scanA_kernel(unsigned* __restrict__ hist,
                                                    unsigned* __restrict__ bucketbase,
                                                    int nblocksA, int nbuckets) {
    __shared__ unsigned tot[256];
    int t = threadIdx.x;
    unsigned total = 0;
    if (t < nbuckets) {
        for (int blk = 0; blk < nblocksA; blk++) {
            unsigned v = hist[t * nblocksA + blk];
            hist[t * nblocksA + blk] = total;
            total += v;
        }
    }
    tot[t] = total;
    __syncthreads();
    unsigned val = tot[t];
    for (int off = 1; off < 256; off <<= 1) {
        unsigned v = (t >= off) ? tot[t - off] : 0u;
        __syncthreads();
        tot[t] += v;
        __syncthreads();
    }
    unsigned ex = tot[t] - val;
    if (t < nbuckets) bucketbase[t] = ex;
    if (t == nbuckets - 1) bucketbase[nbuckets] = ex + val;  // == E
}

// ---- pass A3: scatter (r,c) into bucket-grouped binned[] ----
__global__ __launch_bounds__(256) void scatterA_kernel(const int* __restrict__ rows,
                                                       const int* __restrict__ cols,
                                                       const unsigned* __restrict__ hist,
                                                       const unsigned* __restrict__ bucketbase,
                                                       uint2* __restrict__ binned,
                                                       int E, int nblocksA, int nbuckets) {
    __shared__ unsigned ofs[256];
    int t = threadIdx.x, blk = blockIdx.x;
    if (t < nbuckets) ofs[t] = bucketbase[t] + hist[t * nblocksA + blk];
    __syncthreads();
    int base = blk * CHUNK;
#pragma unroll
    for (int j = 0; j < CHUNK / 256; j++) {
        int i = base + j * 256 + t;
        if (i < E) {
            unsigned c = (unsigned)cols[i];
            unsigned r = (unsigned)rows[i];
            unsigned pos = atomicAdd(&ofs[c >> 9], 1u);
            binned[pos] = make_uint2(r, c);
        }
    }
}

// ---- pass B: per bucket — local count/scan -> rowptr, dinv, srcidx ----
__global__ __launch_bounds__(256) void binB_kernel(const uint2* __restrict__ binned,
                                                   const unsigned* __restrict__ bucketbase,
                                                   int* __restrict__ rowptr,
                                                   float* __restrict__ dinv,
                                                   int* __restrict__ srcidx,
                                                   int N, int E, int nbuckets) {
    __shared__ unsigned cnt[BN + 1];
    __shared__ unsigned sc[BN + 1];
    __shared__ unsigned ps[256];
    int t = threadIdx.x, b = blockIdx.x;
    int lo = b << 9;
    int nn = min(BN, N - lo);
    unsigned s = bucketbase[b], e = bucketbase[b + 1];

    cnt[t] = 0;
    cnt[t + 256] = 0;
    if (t == 0) cnt[BN] = 0;
    __syncthreads();
    for (unsigned i = s + t; i < e; i += 256)
        atomicAdd(&cnt[binned[i].y - lo], 1u);
    __syncthreads();

    // exclusive scan of cnt[0..BN) -> sc[0..BN], sc[BN] = total
    unsigned a0 = cnt[2 * t], a1 = cnt[2 * t + 1];
    ps[t] = a0 + a1;
    __syncthreads();
    unsigned val = ps[t];
    for (int off = 1; off < 256; off <<= 1) {
        unsigned v = (t >= off) ? ps[t - off] : 0u;
        __syncthreads();
        ps[t] += v;
        __syncthreads();
    }
    unsigned ex = ps[t] - val;
    sc[2 * t] = ex;
    sc[2 * t + 1] = ex + a0;
    if (t == 255) sc[BN] = ex + val;
    __syncthreads();

    // rowptr + dinv + cursor init (cursor reuses cnt)
    for (int n = t; n < nn; n += 256) {
        unsigned rp = s + sc[n];
        rowptr[lo + n] = (int)rp;
        dinv[lo + n] = rsqrtf((float)(sc[n + 1] - sc[n]) + 1.0f);
        cnt[n] = rp;
    }
    if (b == nbuckets - 1 && t == 0) rowptr[N] = E;
    __syncthreads();

    // scatter srcidx within this bucket's contiguous region
    for (unsigned i = s + t; i < e; i += 256) {
        uint2 u = binned[i];
        unsigned slot = atomicAdd(&cnt[u.y - lo], 1u);
        srcidx[slot] = (int)u.x;
    }
}

// ---------------- fp32 GEMM: OutH[i,:] = (X[i,:] @ W) * dinv[i], bf16 out ----------
template <int NOUT, bool IN_BF16>
__global__ __launch_bounds__(256) void gemm_scale(const void* __restrict__ Xv,
                                                  const float* __restrict__ W,
                                                  const float* __restrict__ dinv,
                                                  u16* __restrict__ OutH, int nrows) {
    constexpr int LDK = 132;
    constexpr int CPT = NOUT / 16;
    __shared__ float sX[64 * LDK];

    const int t = threadIdx.x;
    const int row0 = blockIdx.x * 64;

    if (IN_BF16) {
        const u16* X = (const u16*)Xv;
        for (int idx = t; idx < 64 * 16; idx += 256) {
            int r = idx >> 4, c = idx & 15;
            int gr = row0 + r;
            float f[8];
            if (gr < nrows) {
                uint4 v = ((const uint4*)X)[(size_t)gr * 16 + c];
                unsigned w[4] = {v.x, v.y, v.z, v.w};
#pragma unroll
                for (int j = 0; j < 4; j++) {
                    f[2 * j] = bflo(w[j]);
                    f[2 * j + 1] = bfhi(w[j]);
                }
            } else {
#pragma unroll
                for (int j = 0; j < 8; j++) f[j] = 0.f;
            }
#pragma unroll
            for (int j = 0; j < 8; j++) sX[r * LDK + c * 8 + j] = f[j];
        }
    } else {
        const float* X = (const float*)Xv;
        for (int idx = t; idx < 64 * 32; idx += 256) {
            int r = idx >> 5, c = idx & 31;
            int gr = row0 + r;
            float4 v = make_float4(0.f, 0.f, 0.f, 0.f);
            if (gr < nrows) v = ((const float4*)X)[(size_t)gr * 32 + c];
            *((float4*)&sX[r * LDK + c * 4]) = v;
        }
    }
    __syncthreads();

    const int cg = t & 15, rg = t >> 4;
    const int j0 = cg * CPT;
    float acc[4][CPT];
#pragma unroll
    for (int i = 0; i < 4; i++)
#pragma unroll
        for (int j = 0; j < CPT; j++) acc[i][j] = 0.f;

#pragma unroll 4
    for (int k = 0; k < 128; k++) {
        float a[4];
#pragma unroll
        for (int i = 0; i < 4; i++) a[i] = sX[(rg * 4 + i) * LDK + k];
        float b[CPT];
        const float4* wp = (const float4*)(W + (size_t)k * NOUT + j0);
#pragma unroll
        for (int j4 = 0; j4 < CPT / 4; j4++) {
            float4 bv = wp[j4];
            b[j4 * 4 + 0] = bv.x; b[j4 * 4 + 1] = bv.y;
            b[j4 * 4 + 2] = bv.z; b[j4 * 4 + 3] = bv.w;
        }
#pragma unroll
        for (int i = 0; i < 4; i++)
#pragma unroll
            for (int j = 0; j < CPT; j++) acc[i][j] = fmaf(a[i], b[j], acc[i][j]);
    }

#pragma unroll
    for (int i = 0; i < 4; i++) {
        int gi = row0 + rg * 4 + i;
        if (gi < nrows) {
            float dv = dinv[gi];
            u16 pk[CPT];
#pragma unroll
            for (int j = 0; j < CPT; j++) pk[j] = f2bf(acc[i][j] * dv);
            if (CPT == 8) {
                uint4 o;
                o.x = pk[0] | ((unsigned)pk[1] << 16);
                o.y = pk[2] | ((unsigned)pk[3] << 16);
                o.z = pk[4] | ((unsigned)pk[5] << 16);
                o.w = pk[6] | ((unsigned)pk[7] << 16);
                *((uint4*)&OutH[(size_t)gi * NOUT + j0]) = o;
            } else {
                uint2 o;
                o.x = pk[0] | ((unsigned)pk[1] << 16);
                o.y = pk[2] | ((unsigned)pk[3] << 16);
                *((uint2*)&OutH[(size_t)gi * NOUT + j0]) = o;
            }
        }
    }
}

// ---- aggregate+finalize: out[c] = [relu](dinv[c]*(Σ_in h'[r] + h'[c]) + b) ----
template <int NH, bool RELU, bool OUT_BF16>
__global__ __launch_bounds__(256) void aggregate(const int* __restrict__ rowptr,
                                                 const int* __restrict__ srcidx,
                                                 const u16* __restrict__ hs,
                                                 const float* __restrict__ dinv,
                                                 const float* __restrict__ bias,
                                                 void* __restrict__ outv, int N) {
    constexpr int WPN = NH / 4;
    int tid = blockIdx.x * 256 + threadIdx.x;
    int node = tid / WPN;
    int fl = tid % WPN;
    if (node >= N) return;

    const uint2* h64 = (const uint2*)hs;
    int start = rowptr[node], end = rowptr[node + 1];

    uint2 v = h64[(size_t)node * WPN + fl];  // self loop h'[c]
    float a0 = bflo(v.x), a1 = bfhi(v.x), a2 = bflo(v.y), a3 = bfhi(v.y);

    int i = start;
    for (; i + 8 <= end; i += 8) {
        int r[8];
#pragma unroll
        for (int j = 0; j < 8; j++) r[j] = srcidx[i + j];
        uint2 u[8];
#pragma unroll
        for (int j = 0; j < 8; j++) u[j] = h64[(size_t)r[j] * WPN + fl];
#pragma unroll
        for (int j = 0; j < 8; j++) {
            a0 += bflo(u[j].x);
            a1 += bfhi(u[j].x);
            a2 += bflo(u[j].y);
            a3 += bfhi(u[j].y);
        }
    }
    for (; i < end; ++i) {
        int r = srcidx[i];
        uint2 u = h64[(size_t)r * WPN + fl];
        a0 += bflo(u.x);
        a1 += bfhi(u.x);
        a2 += bflo(u.y);
        a3 += bfhi(u.y);
    }

    float dv = dinv[node];
    float4 bv = ((const float4*)bias)[fl];
    float o0 = dv * a0 + bv.x;
    float o1 = dv * a1 + bv.y;
    float o2 = dv * a2 + bv.z;
    float o3 = dv * a3 + bv.w;
    if (RELU) {
        o0 = fmaxf(o0, 0.f);
        o1 = fmaxf(o1, 0.f);
        o2 = fmaxf(o2, 0.f);
        o3 = fmaxf(o3, 0.f);
    }
    if (OUT_BF16) {
        uint2 o;
        o.x = (unsigned)f2bf(o0) | ((unsigned)f2bf(o1) << 16);
        o.y = (unsigned)f2bf(o2) | ((unsigned)f2bf(o3) << 16);
        ((uint2*)outv)[tid] = o;
    } else {
        ((float4*)outv)[tid] = make_float4(o0, o1, o2, o3);
    }
}

extern "C" void kernel_launch(void* const* d_in, const int* in_sizes, int n_in,
                              void* d_out, int out_size, void* d_ws, size_t ws_size,
                              hipStream_t stream) {
    const float* x  = (const float*)d_in[0];
    const int*   ei = (const int*)d_in[1];
    const float* W1 = (const float*)d_in[2];
    const float* b1 = (const float*)d_in[3];
    const float* W2 = (const float*)d_in[4];
    const float* b2 = (const float*)d_in[5];

    const int N = in_sizes[0] / 128;
    const int E = in_sizes[1] / 2;
    const int* rows = ei;
    const int* cols = ei + E;

    const int nbuckets = (N + BN - 1) / BN;          // 196 for N=100k (<=256)
    const int nblocksA = (E + CHUNK - 1) / CHUNK;    // 196 for E=1.6M

    char* ws = (char*)d_ws;
    size_t off = 0;
    auto alloc = [&](size_t bytes) -> void* {
        void* p = ws + off;
        off = (off + bytes + 1023) & ~(size_t)1023;
        return p;
    };
    unsigned* hist       = (unsigned*)alloc((size_t)nbuckets * nblocksA * 4);
    unsigned* bucketbase = (unsigned*)alloc((size_t)(nbuckets + 1) * 4);
    uint2*    binned     = (uint2*)alloc((size_t)E * 8);
    int*      rowptr     = (int*)alloc((size_t)(N + 1) * 4);
    float*    dinv       = (float*)alloc((size_t)N * 4);
    int*      srcidx     = (int*)alloc((size_t)E * 4);
    u16*      h1s        = (u16*)alloc((size_t)N * 128 * 2);  // (x@W1)*dinv, bf16
    u16*      h1b        = (u16*)alloc((size_t)N * 128 * 2);  // relu'd layer-1 out
    u16*      h2s        = h1s;                               // reuse

    // CSR build (binned two-level counting sort; no global atomics on hot paths)
    hist_kernel<<<nblocksA, 256, 0, stream>>>(cols, hist, E, nblocksA, nbuckets);
    scanA_kernel<<<1, 256, 0, stream>>>(hist, bucketbase, nblocksA, nbuckets);
    scatterA_kernel<<<nblocksA, 256, 0, stream>>>(rows, cols, hist, bucketbase, binned, E, nblocksA, nbuckets);
    binB_kernel<<<nbuckets, 256, 0, stream>>>(binned, bucketbase, rowptr, dinv, srcidx, N, E, nbuckets);

    // layer 1
    gemm_scale<128, false><<<(N + 63) / 64, 256, 0, stream>>>(x, W1, dinv, h1s, N);
    aggregate<128, true, true><<<(N * 32 + 255) / 256, 256, 0, stream>>>(
        rowptr, srcidx, h1s, dinv, b1, h1b, N);

    // layer 2
    gemm_scale<64, true><<<(N + 63) / 64, 256, 0, stream>>>(h1b, W2, dinv, h2s, N);
    aggregate<64, false, false><<<(N * 16 + 255) / 256, 256, 0, stream>>>(
        rowptr, srcidx, h2s, dinv, b2, d_out, N);
}

// Round 6
// 341.288 us; speedup vs baseline: 6.6322x; 1.2016x over previous
//
#include <hip/hip_runtime.h>
#include <hip/hip_bf16.h>

typedef unsigned short u16;
typedef short bf16x8 __attribute__((ext_vector_type(8)));
typedef float f32x4 __attribute__((ext_vector_type(4)));

__device__ __forceinline__ float bflo(unsigned u) { return __uint_as_float(u << 16); }
__device__ __forceinline__ float bfhi(unsigned u) { return __uint_as_float(u & 0xffff0000u); }
__device__ __forceinline__ u16 f2bf(float f) {
    unsigned u = __float_as_uint(f);
    return (u16)((u + 0x7fffu + ((u >> 16) & 1u)) >> 16);  // RNE
}

#define CHUNK 8192     // edges per block in pass A
#define BN 512         // nodes per bucket (bucket = c >> 9)

// ---- pass A1: per-block bucket histogram ----
__global__ __launch_bounds__(256) void hist_kernel(const int* __restrict__ cols,
                                                   unsigned* __restrict__ hist,
                                                   int E, int nblocksA, int nbuckets) {
    __shared__ unsigned h[256];
    int t = threadIdx.x, blk = blockIdx.x;
    h[t] = 0;
    __syncthreads();
    int base = blk * CHUNK;
#pragma unroll
    for (int j = 0; j < CHUNK / 256; j++) {
        int i = base + j * 256 + t;
        if (i < E) atomicAdd(&h[((unsigned)cols[i]) >> 9], 1u);
    }
    __syncthreads();
    if (t < nbuckets) hist[t * nblocksA + blk] = h[t];
}

// ---- pass A2: per-bucket block prefixes + bucket bases (single WG) ----
__global__ __launch_bounds__(256) void scanA_kernel(unsigned* __restrict__ hist,
                                                    unsigned* __restrict__ bucketbase,
                                                    int nblocksA, int nbuckets) {
    __shared__ unsigned tot[256];
    int t = threadIdx.x;
    unsigned total = 0;
    if (t < nbuckets) {
        for (int blk = 0; blk < nblocksA; blk++) {
            unsigned v = hist[t * nblocksA + blk];
            hist[t * nblocksA + blk] = total;
            total += v;
        }
    }
    tot[t] = total;
    __syncthreads();
    unsigned val = tot[t];
    for (int off = 1; off < 256; off <<= 1) {
        unsigned v = (t >= off) ? tot[t - off] : 0u;
        __syncthreads();
        tot[t] += v;
        __syncthreads();
    }
    unsigned ex = tot[t] - val;
    if (t < nbuckets) bucketbase[t] = ex;
    if (t == nbuckets - 1) bucketbase[nbuckets] = ex + val;  // == E
}

// ---- pass A3: scatter (r,c) into bucket-grouped binned[] ----
__global__ __launch_bounds__(256) void scatterA_kernel(const int* __restrict__ rows,
                                                       const int* __restrict__ cols,
                                                       const unsigned* __restrict__ hist,
                                                       const unsigned* __restrict__ bucketbase,
                                                       uint2* __restrict__ binned,
                                                       int E, int nblocksA, int nbuckets) {
    __shared__ unsigned ofs[256];
    int t = threadIdx.x, blk = blockIdx.x;
    if (t < nbuckets) ofs[t] = bucketbase[t] + hist[t * nblocksA + blk];
    __syncthreads();
    int base = blk * CHUNK;
#pragma unroll
    for (int j = 0; j < CHUNK / 256; j++) {
        int i = base + j * 256 + t;
        if (i < E) {
            unsigned c = (unsigned)cols[i];
            unsigned r = (unsigned)rows[i];
            unsigned pos = atomicAdd(&ofs[c >> 9], 1u);
            binned[pos] = make_uint2(r, c);
        }
    }
}

// ---- pass B: per bucket — local count/scan -> rowptr, dinv, srcidx ----
__global__ __launch_bounds__(256) void binB_kernel(const uint2* __restrict__ binned,
                                                   const unsigned* __restrict__ bucketbase,
                                                   int* __restrict__ rowptr,
                                                   float* __restrict__ dinv,
                                                   int* __restrict__ srcidx,
                                                   int N, int E, int nbuckets) {
    __shared__ unsigned cnt[BN + 1];
    __shared__ unsigned sc[BN + 1];
    __shared__ unsigned ps[256];
    int t = threadIdx.x, b = blockIdx.x;
    int lo = b << 9;
    int nn = min(BN, N - lo);
    unsigned s = bucketbase[b], e = bucketbase[b + 1];

    cnt[t] = 0;
    cnt[t + 256] = 0;
    if (t == 0) cnt[BN] = 0;
    __syncthreads();
    for (unsigned i = s + t; i < e; i += 256)
        atomicAdd(&cnt[binned[i].y - lo], 1u);
    __syncthreads();

    unsigned a0 = cnt[2 * t], a1 = cnt[2 * t + 1];
    ps[t] = a0 + a1;
    __syncthreads();
    unsigned val = ps[t];
    for (int off = 1; off < 256; off <<= 1) {
        unsigned v = (t >= off) ? ps[t - off] : 0u;
        __syncthreads();
        ps[t] += v;
        __syncthreads();
    }
    unsigned ex = ps[t] - val;
    sc[2 * t] = ex;
    sc[2 * t + 1] = ex + a0;
    if (t == 255) sc[BN] = ex + val;
    __syncthreads();

    for (int n = t; n < nn; n += 256) {
        unsigned rp = s + sc[n];
        rowptr[lo + n] = (int)rp;
        dinv[lo + n] = rsqrtf((float)(sc[n + 1] - sc[n]) + 1.0f);
        cnt[n] = rp;
    }
    if (b == nbuckets - 1 && t == 0) rowptr[N] = E;
    __syncthreads();

    for (unsigned i = s + t; i < e; i += 256) {
        uint2 u = binned[i];
        unsigned slot = atomicAdd(&cnt[u.y - lo], 1u);
        srcidx[slot] = (int)u.x;
    }
}

// ---- W -> bf16 transposed: WT[n][k] = bf16(W[k][n]) ----
__global__ __launch_bounds__(256) void prep_wt(const float* __restrict__ W1,
                                               const float* __restrict__ W2,
                                               u16* __restrict__ WT1,
                                               u16* __restrict__ WT2) {
    int t = blockIdx.x * 256 + threadIdx.x;
    if (t < 128 * 128) {
        int n = t >> 7, k = t & 127;
        WT1[n * 128 + k] = f2bf(W1[k * 128 + n]);
    } else if (t < 128 * 128 + 64 * 128) {
        int i = t - 128 * 128;
        int n = i >> 7, k = i & 127;
        WT2[n * 128 + k] = f2bf(W2[k * 64 + n]);
    }
}

// ---- MFMA bf16 GEMM: OutH[i,:] = bf16((X[i,:] @ W) * dinv[i]) ----
// 64 rows/block, 4 waves; wave w owns rows w*16..w*16+15. K=128, N=NOUT.
// A frag: A[m=lane&15][k=q*8+j]; B frag: B[k=q*8+j][n=lane&15]; D: col=lane&15, row=q*4+reg.
template <int NOUT, bool IN_BF16>
__global__ __launch_bounds__(256) void gemm_mfma(const void* __restrict__ Xv,
                                                 const u16* __restrict__ WT,  // [NOUT][128] bf16
                                                 const float* __restrict__ dinv,
                                                 u16* __restrict__ OutH, int nrows) {
    constexpr int LDK = 136;  // bf16 elems/row: 128 + 8 pad
    __shared__ u16 sX[64 * LDK];
    __shared__ u16 sW[NOUT * LDK];

    const int t = threadIdx.x;
    const int wv = t >> 6, lane = t & 63;
    const int m = lane & 15, q = lane >> 4;
    const int row0 = blockIdx.x * 64;

    // stage W^T (already bf16, row-major [n][k])
    for (int idx = t; idx < NOUT * 16; idx += 256) {
        int n = idx >> 4, c = idx & 15;
        *((uint4*)&sW[n * LDK + c * 8]) = ((const uint4*)WT)[idx];
    }
    // stage X rows -> bf16
    if (IN_BF16) {
        const u16* X = (const u16*)Xv;
        for (int idx = t; idx < 64 * 16; idx += 256) {
            int r = idx >> 4, c = idx & 15;
            int gr = row0 + r;
            uint4 v = make_uint4(0u, 0u, 0u, 0u);
            if (gr < nrows) v = ((const uint4*)X)[(size_t)gr * (NOUT == 64 ? 16 : 16) + c];
            *((uint4*)&sX[r * LDK + c * 8]) = v;
        }
    } else {
        const float* X = (const float*)Xv;
        for (int idx = t; idx < 64 * 32; idx += 256) {
            int r = idx >> 5, c = idx & 31;
            int gr = row0 + r;
            float4 v = make_float4(0.f, 0.f, 0.f, 0.f);
            if (gr < nrows) v = ((const float4*)X)[(size_t)gr * 32 + c];
            uint2 o;
            o.x = (unsigned)f2bf(v.x) | ((unsigned)f2bf(v.y) << 16);
            o.y = (unsigned)f2bf(v.z) | ((unsigned)f2bf(v.w) << 16);
            *((uint2*)&sX[r * LDK + c * 4]) = o;
        }
    }
    __syncthreads();

    f32x4 acc[NOUT / 16];
#pragma unroll
    for (int i = 0; i < NOUT / 16; i++) acc[i] = (f32x4){0.f, 0.f, 0.f, 0.f};

#pragma unroll
    for (int ks = 0; ks < 4; ks++) {
        const int k0 = ks * 32 + q * 8;
        bf16x8 a = *((const bf16x8*)&sX[(wv * 16 + m) * LDK + k0]);
#pragma unroll
        for (int nt = 0; nt < NOUT / 16; nt++) {
            bf16x8 b = *((const bf16x8*)&sW[(nt * 16 + m) * LDK + k0]);
            acc[nt] = __builtin_amdgcn_mfma_f32_16x16x32_bf16(a, b, acc[nt], 0, 0, 0);
        }
    }

#pragma unroll
    for (int r = 0; r < 4; r++) {
        int gi = row0 + wv * 16 + q * 4 + r;
        if (gi < nrows) {
            float dv = dinv[gi];
#pragma unroll
            for (int nt = 0; nt < NOUT / 16; nt++) {
                OutH[(size_t)gi * NOUT + nt * 16 + m] = f2bf(acc[nt][r] * dv);
            }
        }
    }
}

// ---- aggregate+finalize: out[c] = [relu](dinv[c]*(Σ_in h'[r] + h'[c]) + b) ----
template <int NH, bool RELU, bool OUT_BF16>
__global__ __launch_bounds__(256) void aggregate(const int* __restrict__ rowptr,
                                                 const int* __restrict__ srcidx,
                                                 const u16* __restrict__ hs,
                                                 const float* __restrict__ dinv,
                                                 const float* __restrict__ bias,
                                                 void* __restrict__ outv, int N) {
    constexpr int WPN = NH / 4;
    int tid = blockIdx.x * 256 + threadIdx.x;
    int node = tid / WPN;
    int fl = tid % WPN;
    if (node >= N) return;

    const uint2* h64 = (const uint2*)hs;
    int start = rowptr[node], end = rowptr[node + 1];

    uint2 v = h64[(size_t)node * WPN + fl];  // self loop h'[c]
    float a0 = bflo(v.x), a1 = bfhi(v.x), a2 = bflo(v.y), a3 = bfhi(v.y);

    int i = start;
    for (; i + 8 <= end; i += 8) {
        int r[8];
#pragma unroll
        for (int j = 0; j < 8; j++) r[j] = srcidx[i + j];
        uint2 u[8];
#pragma unroll
        for (int j = 0; j < 8; j++) u[j] = h64[(size_t)r[j] * WPN + fl];
#pragma unroll
        for (int j = 0; j < 8; j++) {
            a0 += bflo(u[j].x);
            a1 += bfhi(u[j].x);
            a2 += bflo(u[j].y);
            a3 += bfhi(u[j].y);
        }
    }
    for (; i < end; ++i) {
        int r = srcidx[i];
        uint2 u = h64[(size_t)r * WPN + fl];
        a0 += bflo(u.x);
        a1 += bfhi(u.x);
        a2 += bflo(u.y);
        a3 += bfhi(u.y);
    }

    float dv = dinv[node];
    float4 bv = ((const float4*)bias)[fl];
    float o0 = dv * a0 + bv.x;
    float o1 = dv * a1 + bv.y;
    float o2 = dv * a2 + bv.z;
    float o3 = dv * a3 + bv.w;
    if (RELU) {
        o0 = fmaxf(o0, 0.f);
        o1 = fmaxf(o1, 0.f);
        o2 = fmaxf(o2, 0.f);
        o3 = fmaxf(o3, 0.f);
    }
    if (OUT_BF16) {
        uint2 o;
        o.x = (unsigned)f2bf(o0) | ((unsigned)f2bf(o1) << 16);
        o.y = (unsigned)f2bf(o2) | ((unsigned)f2bf(o3) << 16);
        ((uint2*)outv)[tid] = o;
    } else {
        ((float4*)outv)[tid] = make_float4(o0, o1, o2, o3);
    }
}

extern "C" void kernel_launch(void* const* d_in, const int* in_sizes, int n_in,
                              void* d_out, int out_size, void* d_ws, size_t ws_size,
                              hipStream_t stream) {
    const float* x  = (const float*)d_in[0];
    const int*   ei = (const int*)d_in[1];
    const float* W1 = (const float*)d_in[2];
    const float* b1 = (const float*)d_in[3];
    const float* W2 = (const float*)d_in[4];
    const float* b2 = (const float*)d_in[5];

    const int N = in_sizes[0] / 128;
    const int E = in_sizes[1] / 2;
    const int* rows = ei;
    const int* cols = ei + E;

    const int nbuckets = (N + BN - 1) / BN;          // 196 for N=100k (<=256)
    const int nblocksA = (E + CHUNK - 1) / CHUNK;    // 196 for E=1.6M

    char* ws = (char*)d_ws;
    size_t off = 0;
    auto alloc = [&](size_t bytes) -> void* {
        void* p = ws + off;
        off = (off + bytes + 1023) & ~(size_t)1023;
        return p;
    };
    unsigned* hist       = (unsigned*)alloc((size_t)nbuckets * nblocksA * 4);
    unsigned* bucketbase = (unsigned*)alloc((size_t)(nbuckets + 1) * 4);
    uint2*    binned     = (uint2*)alloc((size_t)E * 8);
    int*      rowptr     = (int*)alloc((size_t)(N + 1) * 4);
    float*    dinv       = (float*)alloc((size_t)N * 4);
    int*      srcidx     = (int*)alloc((size_t)E * 4);
    u16*      WT1        = (u16*)alloc((size_t)128 * 128 * 2);
    u16*      WT2        = (u16*)alloc((size_t)64 * 128 * 2);
    u16*      h1s        = (u16*)alloc((size_t)N * 128 * 2);  // (x@W1)*dinv, bf16
    u16*      h1b        = (u16*)alloc((size_t)N * 128 * 2);  // relu'd layer-1 out
    u16*      h2s        = h1s;                               // reuse

    // CSR build (binned two-level counting sort)
    hist_kernel<<<nblocksA, 256, 0, stream>>>(cols, hist, E, nblocksA, nbuckets);
    scanA_kernel<<<1, 256, 0, stream>>>(hist, bucketbase, nblocksA, nbuckets);
    scatterA_kernel<<<nblocksA, 256, 0, stream>>>(rows, cols, hist, bucketbase, binned, E, nblocksA, nbuckets);
    binB_kernel<<<nbuckets, 256, 0, stream>>>(binned, bucketbase, rowptr, dinv, srcidx, N, E, nbuckets);

    prep_wt<<<96, 256, 0, stream>>>(W1, W2, WT1, WT2);

    // layer 1
    gemm_mfma<128, false><<<(N + 63) / 64, 256, 0, stream>>>(x, WT1, dinv, h1s, N);
    aggregate<128, true, true><<<(N * 32 + 255) / 256, 256, 0, stream>>>(
        rowptr, srcidx, h1s, dinv, b1, h1b, N);

    // layer 2
    gemm_mfma<64, true><<<(N + 63) / 64, 256, 0, stream>>>(h1b, WT2, dinv, h2s, N);
    aggregate<64, false, false><<<(N * 16 + 255) / 256, 256, 0, stream>>>(
        rowptr, srcidx, h2s, dinv, b2, d_out, N);
}

// Round 7
// 330.979 us; speedup vs baseline: 6.8388x; 1.0311x over previous
//
#include <hip/hip_runtime.h>
#include <hip/hip_bf16.h>

typedef unsigned short u16;
typedef short bf16x8 __attribute__((ext_vector_type(8)));
typedef float f32x4 __attribute__((ext_vector_type(4)));

__device__ __forceinline__ float bflo(unsigned u) { return __uint_as_float(u << 16); }
__device__ __forceinline__ float bfhi(unsigned u) { return __uint_as_float(u & 0xffff0000u); }
__device__ __forceinline__ u16 f2bf(float f) {
    unsigned u = __float_as_uint(f);
    return (u16)((u + 0x7fffu + ((u >> 16) & 1u)) >> 16);  // RNE
}

#define CHUNK 8192     // edges per block in pass A
#define BN 512         // nodes per bucket (bucket = c >> 9)

// ---- pass A1: per-block bucket histogram (hist layout: [blk][bucket]) ----
__global__ __launch_bounds__(256) void hist_kernel(const int* __restrict__ cols,
                                                   unsigned* __restrict__ hist,
                                                   int E, int nbuckets) {
    __shared__ unsigned h[256];
    int t = threadIdx.x, blk = blockIdx.x;
    h[t] = 0;
    __syncthreads();
    int base = blk * CHUNK;
#pragma unroll
    for (int j = 0; j < CHUNK / 256; j++) {
        int i = base + j * 256 + t;
        if (i < E) atomicAdd(&h[((unsigned)cols[i]) >> 9], 1u);
    }
    __syncthreads();
    if (t < nbuckets) hist[blk * nbuckets + t] = h[t];
}

// ---- pass A2: per-bucket block prefixes + bucket bases (single WG, coalesced) ----
__global__ __launch_bounds__(256) void scanA_kernel(unsigned* __restrict__ hist,
                                                    unsigned* __restrict__ bucketbase,
                                                    int nblocksA, int nbuckets) {
    __shared__ unsigned tot[256];
    int t = threadIdx.x;
    unsigned total = 0;
    for (int blk = 0; blk < nblocksA; blk++) {
        unsigned v = (t < nbuckets) ? hist[blk * nbuckets + t] : 0u;
        if (t < nbuckets) hist[blk * nbuckets + t] = total;
        total += v;
    }
    tot[t] = total;
    __syncthreads();
    unsigned val = tot[t];
    for (int off = 1; off < 256; off <<= 1) {
        unsigned v = (t >= off) ? tot[t - off] : 0u;
        __syncthreads();
        tot[t] += v;
        __syncthreads();
    }
    unsigned ex = tot[t] - val;
    if (t < nbuckets) bucketbase[t] = ex;
    if (t == nbuckets - 1) bucketbase[nbuckets] = ex + val;  // == E
}

// ---- pass A3: scatter (r,c) into bucket-grouped binned[] ----
__global__ __launch_bounds__(256) void scatterA_kernel(const int* __restrict__ rows,
                                                       const int* __restrict__ cols,
                                                       const unsigned* __restrict__ hist,
                                                       const unsigned* __restrict__ bucketbase,
                                                       uint2* __restrict__ binned,
                                                       int E, int nbuckets) {
    __shared__ unsigned ofs[256];
    int t = threadIdx.x, blk = blockIdx.x;
    if (t < nbuckets) ofs[t] = bucketbase[t] + hist[blk * nbuckets + t];
    __syncthreads();
    int base = blk * CHUNK;
#pragma unroll
    for (int j = 0; j < CHUNK / 256; j++) {
        int i = base + j * 256 + t;
        if (i < E) {
            unsigned c = (unsigned)cols[i];
            unsigned r = (unsigned)rows[i];
            unsigned pos = atomicAdd(&ofs[c >> 9], 1u);
            binned[pos] = make_uint2(r, c);
        }
    }
}

// ---- pass B: per bucket — local count/scan -> rowptr, dinv, srcidx ----
__global__ __launch_bounds__(256) void binB_kernel(const uint2* __restrict__ binned,
                                                   const unsigned* __restrict__ bucketbase,
                                                   int* __restrict__ rowptr,
                                                   float* __restrict__ dinv,
                                                   int* __restrict__ srcidx,
                                                   int N, int E, int nbuckets) {
    __shared__ unsigned cnt[BN + 1];
    __shared__ unsigned sc[BN + 1];
    __shared__ unsigned ps[256];
    int t = threadIdx.x, b = blockIdx.x;
    int lo = b << 9;
    int nn = min(BN, N - lo);
    unsigned s = bucketbase[b], e = bucketbase[b + 1];

    cnt[t] = 0;
    cnt[t + 256] = 0;
    if (t == 0) cnt[BN] = 0;
    __syncthreads();
    for (unsigned i = s + t; i < e; i += 256)
        atomicAdd(&cnt[binned[i].y - lo], 1u);
    __syncthreads();

    unsigned a0 = cnt[2 * t], a1 = cnt[2 * t + 1];
    ps[t] = a0 + a1;
    __syncthreads();
    unsigned val = ps[t];
    for (int off = 1; off < 256; off <<= 1) {
        unsigned v = (t >= off) ? ps[t - off] : 0u;
        __syncthreads();
        ps[t] += v;
        __syncthreads();
    }
    unsigned ex = ps[t] - val;
    sc[2 * t] = ex;
    sc[2 * t + 1] = ex + a0;
    if (t == 255) sc[BN] = ex + val;
    __syncthreads();

    for (int n = t; n < nn; n += 256) {
        unsigned rp = s + sc[n];
        rowptr[lo + n] = (int)rp;
        dinv[lo + n] = rsqrtf((float)(sc[n + 1] - sc[n]) + 1.0f);
        cnt[n] = rp;
    }
    if (b == nbuckets - 1 && t == 0) rowptr[N] = E;
    __syncthreads();

    for (unsigned i = s + t; i < e; i += 256) {
        uint2 u = binned[i];
        unsigned slot = atomicAdd(&cnt[u.y - lo], 1u);
        srcidx[slot] = (int)u.x;
    }
}

// ---- W -> bf16 transposed: WT[n][k] = bf16(W[k][n]) ----
__global__ __launch_bounds__(256) void prep_wt(const float* __restrict__ W1,
                                               const float* __restrict__ W2,
                                               u16* __restrict__ WT1,
                                               u16* __restrict__ WT2) {
    int t = blockIdx.x * 256 + threadIdx.x;
    if (t < 128 * 128) {
        int n = t >> 7, k = t & 127;
        WT1[n * 128 + k] = f2bf(W1[k * 128 + n]);
    } else if (t < 128 * 128 + 64 * 128) {
        int i = t - 128 * 128;
        int n = i >> 7, k = i & 127;
        WT2[n * 128 + k] = f2bf(W2[k * 64 + n]);
    }
}

// ---- MFMA bf16 GEMM: OutH[i,:] = bf16((X[i,:] @ W) * dinv[i]) ----
template <int NOUT, bool IN_BF16>
__global__ __launch_bounds__(256) void gemm_mfma(const void* __restrict__ Xv,
                                                 const u16* __restrict__ WT,  // [NOUT][128] bf16
                                                 const float* __restrict__ dinv,
                                                 u16* __restrict__ OutH, int nrows) {
    constexpr int LDK = 136;
    __shared__ u16 sX[64 * LDK];
    __shared__ u16 sW[NOUT * LDK];

    const int t = threadIdx.x;
    const int wv = t >> 6, lane = t & 63;
    const int m = lane & 15, q = lane >> 4;
    const int row0 = blockIdx.x * 64;

    for (int idx = t; idx < NOUT * 16; idx += 256) {
        int n = idx >> 4, c = idx & 15;
        *((uint4*)&sW[n * LDK + c * 8]) = ((const uint4*)WT)[idx];
    }
    if (IN_BF16) {
        const u16* X = (const u16*)Xv;
        for (int idx = t; idx < 64 * 16; idx += 256) {
            int r = idx >> 4, c = idx & 15;
            int gr = row0 + r;
            uint4 v = make_uint4(0u, 0u, 0u, 0u);
            if (gr < nrows) v = ((const uint4*)X)[(size_t)gr * 16 + c];
            *((uint4*)&sX[r * LDK + c * 8]) = v;
        }
    } else {
        const float* X = (const float*)Xv;
        for (int idx = t; idx < 64 * 32; idx += 256) {
            int r = idx >> 5, c = idx & 31;
            int gr = row0 + r;
            float4 v = make_float4(0.f, 0.f, 0.f, 0.f);
            if (gr < nrows) v = ((const float4*)X)[(size_t)gr * 32 + c];
            uint2 o;
            o.x = (unsigned)f2bf(v.x) | ((unsigned)f2bf(v.y) << 16);
            o.y = (unsigned)f2bf(v.z) | ((unsigned)f2bf(v.w) << 16);
            *((uint2*)&sX[r * LDK + c * 4]) = o;
        }
    }
    __syncthreads();

    f32x4 acc[NOUT / 16];
#pragma unroll
    for (int i = 0; i < NOUT / 16; i++) acc[i] = (f32x4){0.f, 0.f, 0.f, 0.f};

#pragma unroll
    for (int ks = 0; ks < 4; ks++) {
        const int k0 = ks * 32 + q * 8;
        bf16x8 a = *((const bf16x8*)&sX[(wv * 16 + m) * LDK + k0]);
#pragma unroll
        for (int nt = 0; nt < NOUT / 16; nt++) {
            bf16x8 b = *((const bf16x8*)&sW[(nt * 16 + m) * LDK + k0]);
            acc[nt] = __builtin_amdgcn_mfma_f32_16x16x32_bf16(a, b, acc[nt], 0, 0, 0);
        }
    }

#pragma unroll
    for (int r = 0; r < 4; r++) {
        int gi = row0 + wv * 16 + q * 4 + r;
        if (gi < nrows) {
            float dv = dinv[gi];
#pragma unroll
            for (int nt = 0; nt < NOUT / 16; nt++) {
                OutH[(size_t)gi * NOUT + nt * 16 + m] = f2bf(acc[nt][r] * dv);
            }
        }
    }
}

// ---- aggregate+finalize: out[c] = [relu](dinv[c]*(Σ_in h'[r] + h'[c]) + b) ----
// WPN = NH/8 lanes per node; each lane owns 8 features (uint4 = 4 bf16-pairs).
// Batch-8 / batch-4 / scalar tail keeps ≥4 independent gathers in flight.
template <int NH, bool RELU, bool OUT_BF16>
__global__ __launch_bounds__(256) void aggregate(const int* __restrict__ rowptr,
                                                 const int* __restrict__ srcidx,
                                                 const u16* __restrict__ hs,
                                                 const float* __restrict__ dinv,
                                                 const float* __restrict__ bias,
                                                 void* __restrict__ outv, int N) {
    constexpr int WPN = NH / 8;
    int tid = blockIdx.x * 256 + threadIdx.x;
    int node = tid / WPN;
    int fl = tid % WPN;
    if (node >= N) return;

    const uint4* h128 = (const uint4*)hs;
    int start = rowptr[node], end = rowptr[node + 1];

    float a[8];
    {
        uint4 v = h128[(size_t)node * WPN + fl];  // self loop h'[c]
        a[0] = bflo(v.x); a[1] = bfhi(v.x); a[2] = bflo(v.y); a[3] = bfhi(v.y);
        a[4] = bflo(v.z); a[5] = bfhi(v.z); a[6] = bflo(v.w); a[7] = bfhi(v.w);
    }

    int i = start;
    for (; i + 8 <= end; i += 8) {
        int r[8];
#pragma unroll
        for (int j = 0; j < 8; j++) r[j] = srcidx[i + j];
        uint4 u[8];
#pragma unroll
        for (int j = 0; j < 8; j++) u[j] = h128[(size_t)r[j] * WPN + fl];
#pragma unroll
        for (int j = 0; j < 8; j++) {
            a[0] += bflo(u[j].x); a[1] += bfhi(u[j].x);
            a[2] += bflo(u[j].y); a[3] += bfhi(u[j].y);
            a[4] += bflo(u[j].z); a[5] += bfhi(u[j].z);
            a[6] += bflo(u[j].w); a[7] += bfhi(u[j].w);
        }
    }
    if (i + 4 <= end) {
        int r[4];
#pragma unroll
        for (int j = 0; j < 4; j++) r[j] = srcidx[i + j];
        uint4 u[4];
#pragma unroll
        for (int j = 0; j < 4; j++) u[j] = h128[(size_t)r[j] * WPN + fl];
#pragma unroll
        for (int j = 0; j < 4; j++) {
            a[0] += bflo(u[j].x); a[1] += bfhi(u[j].x);
            a[2] += bflo(u[j].y); a[3] += bfhi(u[j].y);
            a[4] += bflo(u[j].z); a[5] += bfhi(u[j].z);
            a[6] += bflo(u[j].w); a[7] += bfhi(u[j].w);
        }
        i += 4;
    }
    for (; i < end; ++i) {
        uint4 u = h128[(size_t)srcidx[i] * WPN + fl];
        a[0] += bflo(u.x); a[1] += bfhi(u.x);
        a[2] += bflo(u.y); a[3] += bfhi(u.y);
        a[4] += bflo(u.z); a[5] += bfhi(u.z);
        a[6] += bflo(u.w); a[7] += bfhi(u.w);
    }

    float dv = dinv[node];
    float4 bv0 = ((const float4*)bias)[2 * fl];
    float4 bv1 = ((const float4*)bias)[2 * fl + 1];
    float o[8];
    o[0] = dv * a[0] + bv0.x; o[1] = dv * a[1] + bv0.y;
    o[2] = dv * a[2] + bv0.z; o[3] = dv * a[3] + bv0.w;
    o[4] = dv * a[4] + bv1.x; o[5] = dv * a[5] + bv1.y;
    o[6] = dv * a[6] + bv1.z; o[7] = dv * a[7] + bv1.w;
    if (RELU) {
#pragma unroll
        for (int j = 0; j < 8; j++) o[j] = fmaxf(o[j], 0.f);
    }
    if (OUT_BF16) {
        uint4 w;
        w.x = (unsigned)f2bf(o[0]) | ((unsigned)f2bf(o[1]) << 16);
        w.y = (unsigned)f2bf(o[2]) | ((unsigned)f2bf(o[3]) << 16);
        w.z = (unsigned)f2bf(o[4]) | ((unsigned)f2bf(o[5]) << 16);
        w.w = (unsigned)f2bf(o[6]) | ((unsigned)f2bf(o[7]) << 16);
        ((uint4*)outv)[tid] = w;
    } else {
        ((float4*)outv)[2 * tid] = make_float4(o[0], o[1], o[2], o[3]);
        ((float4*)outv)[2 * tid + 1] = make_float4(o[4], o[5], o[6], o[7]);
    }
}

extern "C" void kernel_launch(void* const* d_in, const int* in_sizes, int n_in,
                              void* d_out, int out_size, void* d_ws, size_t ws_size,
                              hipStream_t stream) {
    const float* x  = (const float*)d_in[0];
    const int*   ei = (const int*)d_in[1];
    const float* W1 = (const float*)d_in[2];
    const float* b1 = (const float*)d_in[3];
    const float* W2 = (const float*)d_in[4];
    const float* b2 = (const float*)d_in[5];

    const int N = in_sizes[0] / 128;
    const int E = in_sizes[1] / 2;
    const int* rows = ei;
    const int* cols = ei + E;

    const int nbuckets = (N + BN - 1) / BN;          // 196 for N=100k (<=256)
    const int nblocksA = (E + CHUNK - 1) / CHUNK;    // 196 for E=1.6M

    char* ws = (char*)d_ws;
    size_t off = 0;
    auto alloc = [&](size_t bytes) -> void* {
        void* p = ws + off;
        off = (off + bytes + 1023) & ~(size_t)1023;
        return p;
    };
    unsigned* hist       = (unsigned*)alloc((size_t)nbuckets * nblocksA * 4);
    unsigned* bucketbase = (unsigned*)alloc((size_t)(nbuckets + 1) * 4);
    uint2*    binned     = (uint2*)alloc((size_t)E * 8);
    int*      rowptr     = (int*)alloc((size_t)(N + 1) * 4);
    float*    dinv       = (float*)alloc((size_t)N * 4);
    int*      srcidx     = (int*)alloc((size_t)E * 4);
    u16*      WT1        = (u16*)alloc((size_t)128 * 128 * 2);
    u16*      WT2        = (u16*)alloc((size_t)64 * 128 * 2);
    u16*      h1s        = (u16*)alloc((size_t)N * 128 * 2);
    u16*      h1b        = (u16*)alloc((size_t)N * 128 * 2);
    u16*      h2s        = h1s;

    // CSR build (binned two-level counting sort)
    hist_kernel<<<nblocksA, 256, 0, stream>>>(cols, hist, E, nbuckets);
    scanA_kernel<<<1, 256, 0, stream>>>(hist, bucketbase, nblocksA, nbuckets);
    scatterA_kernel<<<nblocksA, 256, 0, stream>>>(rows, cols, hist, bucketbase, binned, E, nbuckets);
    binB_kernel<<<nbuckets, 256, 0, stream>>>(binned, bucketbase, rowptr, dinv, srcidx, N, E, nbuckets);

    prep_wt<<<96, 256, 0, stream>>>(W1, W2, WT1, WT2);

    // layer 1
    gemm_mfma<128, false><<<(N + 63) / 64, 256, 0, stream>>>(x, WT1, dinv, h1s, N);
    aggregate<128, true, true><<<(N * 16 + 255) / 256, 256, 0, stream>>>(
        rowptr, srcidx, h1s, dinv, b1, h1b, N);

    // layer 2
    gemm_mfma<64, true><<<(N + 63) / 64, 256, 0, stream>>>(h1b, WT2, dinv, h2s, N);
    aggregate<64, false, false><<<(N * 8 + 255) / 256, 256, 0, stream>>>(
        rowptr, srcidx, h2s, dinv, b2, d_out, N);
}

// Round 8
// 285.953 us; speedup vs baseline: 7.9156x; 1.1575x over previous
//
#include <hip/hip_runtime.h>
#include <hip/hip_bf16.h>

typedef unsigned short u16;
typedef short bf16x8 __attribute__((ext_vector_type(8)));
typedef float f32x4 __attribute__((ext_vector_type(4)));

__device__ __forceinline__ float bflo(unsigned u) { return __uint_as_float(u << 16); }
__device__ __forceinline__ float bfhi(unsigned u) { return __uint_as_float(u & 0xffff0000u); }
__device__ __forceinline__ u16 f2bf(float f) {
    unsigned u = __float_as_uint(f);
    return (u16)((u + 0x7fffu + ((u >> 16) & 1u)) >> 16);  // RNE
}

#define CHUNK 8192     // edges per block in pass A
#define BN 512         // nodes per bucket (bucket = c >> 9)

// ---- pass A1: per-block bucket histogram (hist layout: [blk][bucket]) ----
__global__ __launch_bounds__(256) void hist_kernel(const int* __restrict__ cols,
                                                   unsigned* __restrict__ hist,
                                                   int E, int nbuckets) {
    __shared__ unsigned h[256];
    int t = threadIdx.x, blk = blockIdx.x;
    h[t] = 0;
    __syncthreads();
    int base = blk * CHUNK;
#pragma unroll
    for (int j = 0; j < CHUNK / 256; j++) {
        int i = base + j * 256 + t;
        if (i < E) atomicAdd(&h[((unsigned)cols[i]) >> 9], 1u);
    }
    __syncthreads();
    if (t < nbuckets) hist[blk * nbuckets + t] = h[t];
}

// ---- pass A2a: per-bucket prefix over blocks (one WG per bucket) ----
__global__ __launch_bounds__(256) void scanA1_kernel(unsigned* __restrict__ hist,
                                                     unsigned* __restrict__ totals,
                                                     int nblocksA, int nbuckets) {
    __shared__ unsigned s[256];
    int t = threadIdx.x, b = blockIdx.x;
    unsigned val = (t < nblocksA) ? hist[t * nbuckets + b] : 0u;
    s[t] = val;
    __syncthreads();
    for (int off = 1; off < 256; off <<= 1) {
        unsigned v = (t >= off) ? s[t - off] : 0u;
        __syncthreads();
        s[t] += v;
        __syncthreads();
    }
    if (t < nblocksA) hist[t * nbuckets + b] = s[t] - val;  // exclusive
    if (t == 255) totals[b] = s[255];
}

// ---- pass A2b: bucket bases (single WG) ----
__global__ __launch_bounds__(256) void scanA2_kernel(const unsigned* __restrict__ totals,
                                                     unsigned* __restrict__ bucketbase,
                                                     int nbuckets) {
    __shared__ unsigned s[256];
    int t = threadIdx.x;
    unsigned val = (t < nbuckets) ? totals[t] : 0u;
    s[t] = val;
    __syncthreads();
    for (int off = 1; off < 256; off <<= 1) {
        unsigned v = (t >= off) ? s[t - off] : 0u;
        __syncthreads();
        s[t] += v;
        __syncthreads();
    }
    unsigned ex = s[t] - val;
    if (t < nbuckets) bucketbase[t] = ex;
    if (t == nbuckets - 1) bucketbase[nbuckets] = ex + val;  // == E
}

// ---- pass A3: LDS-staged scatter -> coalesced bucket-group writes ----
__global__ __launch_bounds__(256) void scatterA_kernel(const int* __restrict__ rows,
                                                       const int* __restrict__ cols,
                                                       const unsigned* __restrict__ hist,
                                                       const unsigned* __restrict__ bucketbase,
                                                       uint2* __restrict__ binned,
                                                       int E, int nbuckets) {
    __shared__ uint2 sp[CHUNK];        // 64 KB staging
    __shared__ unsigned lstart[256];   // LDS group starts
    __shared__ unsigned lcur[256];     // cursors
    __shared__ unsigned gbase[256];    // global base per bucket for this block
    int t = threadIdx.x, blk = blockIdx.x;
    int base = blk * CHUNK;
    int cnt = min(CHUNK, E - base);

    lcur[t] = 0;
    __syncthreads();
    // count
    for (int i = t; i < cnt; i += 256)
        atomicAdd(&lcur[((unsigned)cols[base + i]) >> 9], 1u);
    __syncthreads();
    // exclusive scan of counts -> lstart
    unsigned val = lcur[t];
    lstart[t] = val;
    __syncthreads();
    for (int off = 1; off < 256; off <<= 1) {
        unsigned v = (t >= off) ? lstart[t - off] : 0u;
        __syncthreads();
        lstart[t] += v;
        __syncthreads();
    }
    unsigned ex = lstart[t] - val;
    __syncthreads();
    lstart[t] = ex;
    lcur[t] = ex;
    if (t < nbuckets) gbase[t] = bucketbase[t] + hist[blk * nbuckets + t];
    __syncthreads();
    // place into LDS grouped by bucket
    for (int i = t; i < cnt; i += 256) {
        unsigned c = (unsigned)cols[base + i];
        unsigned r = (unsigned)rows[base + i];
        unsigned pos = atomicAdd(&lcur[c >> 9], 1u);
        sp[pos] = make_uint2(r, c);
    }
    __syncthreads();
    // write out: consecutive LDS slots -> consecutive global slots per group
    for (int i = t; i < cnt; i += 256) {
        uint2 u = sp[i];
        unsigned g = u.y >> 9;
        binned[gbase[g] + (unsigned)i - lstart[g]] = u;
    }
}

// ---- pass B: per bucket — local count/scan -> rowptr, dinv, srcidx ----
__global__ __launch_bounds__(256) void binB_kernel(const uint2* __restrict__ binned,
                                                   const unsigned* __restrict__ bucketbase,
                                                   int* __restrict__ rowptr,
                                                   float* __restrict__ dinv,
                                                   int* __restrict__ srcidx,
                                                   int N, int E, int nbuckets) {
    __shared__ unsigned cnt[BN + 1];
    __shared__ unsigned sc[BN + 1];
    __shared__ unsigned ps[256];
    int t = threadIdx.x, b = blockIdx.x;
    int lo = b << 9;
    int nn = min(BN, N - lo);
    unsigned s = bucketbase[b], e = bucketbase[b + 1];

    cnt[t] = 0;
    cnt[t + 256] = 0;
    if (t == 0) cnt[BN] = 0;
    __syncthreads();
    for (unsigned i = s + t; i < e; i += 256)
        atomicAdd(&cnt[binned[i].y - lo], 1u);
    __syncthreads();

    unsigned a0 = cnt[2 * t], a1 = cnt[2 * t + 1];
    ps[t] = a0 + a1;
    __syncthreads();
    unsigned val = ps[t];
    for (int off = 1; off < 256; off <<= 1) {
        unsigned v = (t >= off) ? ps[t - off] : 0u;
        __syncthreads();
        ps[t] += v;
        __syncthreads();
    }
    unsigned ex = ps[t] - val;
    sc[2 * t] = ex;
    sc[2 * t + 1] = ex + a0;
    if (t == 255) sc[BN] = ex + val;
    __syncthreads();

    for (int n = t; n < nn; n += 256) {
        unsigned rp = s + sc[n];
        rowptr[lo + n] = (int)rp;
        dinv[lo + n] = rsqrtf((float)(sc[n + 1] - sc[n]) + 1.0f);
        cnt[n] = rp;
    }
    if (b == nbuckets - 1 && t == 0) rowptr[N] = E;
    __syncthreads();

    for (unsigned i = s + t; i < e; i += 256) {
        uint2 u = binned[i];
        unsigned slot = atomicAdd(&cnt[u.y - lo], 1u);
        srcidx[slot] = (int)u.x;
    }
}

// ---- W -> bf16 transposed: WT[n][k] = bf16(W[k][n]) ----
__global__ __launch_bounds__(256) void prep_wt(const float* __restrict__ W1,
                                               const float* __restrict__ W2,
                                               u16* __restrict__ WT1,
                                               u16* __restrict__ WT2) {
    int t = blockIdx.x * 256 + threadIdx.x;
    if (t < 128 * 128) {
        int n = t >> 7, k = t & 127;
        WT1[n * 128 + k] = f2bf(W1[k * 128 + n]);
    } else if (t < 128 * 128 + 64 * 128) {
        int i = t - 128 * 128;
        int n = i >> 7, k = i & 127;
        WT2[n * 128 + k] = f2bf(W2[k * 64 + n]);
    }
}

// ---- MFMA bf16 GEMM: OutH[i,:] = bf16((X[i,:] @ W) * dinv[i]) ----
template <int NOUT, bool IN_BF16>
__global__ __launch_bounds__(256) void gemm_mfma(const void* __restrict__ Xv,
                                                 const u16* __restrict__ WT,  // [NOUT][128] bf16
                                                 const float* __restrict__ dinv,
                                                 u16* __restrict__ OutH, int nrows) {
    constexpr int LDK = 136;
    __shared__ u16 sX[64 * LDK];
    __shared__ u16 sW[NOUT * LDK];

    const int t = threadIdx.x;
    const int wv = t >> 6, lane = t & 63;
    const int m = lane & 15, q = lane >> 4;
    const int row0 = blockIdx.x * 64;

    for (int idx = t; idx < NOUT * 16; idx += 256) {
        int n = idx >> 4, c = idx & 15;
        *((uint4*)&sW[n * LDK + c * 8]) = ((const uint4*)WT)[idx];
    }
    if (IN_BF16) {
        const u16* X = (const u16*)Xv;
        for (int idx = t; idx < 64 * 16; idx += 256) {
            int r = idx >> 4, c = idx & 15;
            int gr = row0 + r;
            uint4 v = make_uint4(0u, 0u, 0u, 0u);
            if (gr < nrows) v = ((const uint4*)X)[(size_t)gr * 16 + c];
            *((uint4*)&sX[r * LDK + c * 8]) = v;
        }
    } else {
        const float* X = (const float*)Xv;
        for (int idx = t; idx < 64 * 32; idx += 256) {
            int r = idx >> 5, c = idx & 31;
            int gr = row0 + r;
            float4 v = make_float4(0.f, 0.f, 0.f, 0.f);
            if (gr < nrows) v = ((const float4*)X)[(size_t)gr * 32 + c];
            uint2 o;
            o.x = (unsigned)f2bf(v.x) | ((unsigned)f2bf(v.y) << 16);
            o.y = (unsigned)f2bf(v.z) | ((unsigned)f2bf(v.w) << 16);
            *((uint2*)&sX[r * LDK + c * 4]) = o;
        }
    }
    __syncthreads();

    f32x4 acc[NOUT / 16];
#pragma unroll
    for (int i = 0; i < NOUT / 16; i++) acc[i] = (f32x4){0.f, 0.f, 0.f, 0.f};

#pragma unroll
    for (int ks = 0; ks < 4; ks++) {
        const int k0 = ks * 32 + q * 8;
        bf16x8 a = *((const bf16x8*)&sX[(wv * 16 + m) * LDK + k0]);
#pragma unroll
        for (int nt = 0; nt < NOUT / 16; nt++) {
            bf16x8 b = *((const bf16x8*)&sW[(nt * 16 + m) * LDK + k0]);
            acc[nt] = __builtin_amdgcn_mfma_f32_16x16x32_bf16(a, b, acc[nt], 0, 0, 0);
        }
    }

#pragma unroll
    for (int r = 0; r < 4; r++) {
        int gi = row0 + wv * 16 + q * 4 + r;
        if (gi < nrows) {
            float dv = dinv[gi];
#pragma unroll
            for (int nt = 0; nt < NOUT / 16; nt++) {
                OutH[(size_t)gi * NOUT + nt * 16 + m] = f2bf(acc[nt][r] * dv);
            }
        }
    }
}

// ---- aggregate+finalize: out[c] = [relu](dinv[c]*(Σ_in h'[r] + h'[c]) + b) ----
// WPN = NH/8 lanes per node; each lane owns 8 features (uint4).
// Batch-8 with software-pipelined index preload: next batch's srcidx issue
// before consuming current batch's gathers.
template <int NH, bool RELU, bool OUT_BF16>
__global__ __launch_bounds__(256) void aggregate(const int* __restrict__ rowptr,
                                                 const int* __restrict__ srcidx,
                                                 const u16* __restrict__ hs,
                                                 const float* __restrict__ dinv,
                                                 const float* __restrict__ bias,
                                                 void* __restrict__ outv, int N) {
    constexpr int WPN = NH / 8;
    int tid = blockIdx.x * 256 + threadIdx.x;
    int node = tid / WPN;
    int fl = tid % WPN;
    if (node >= N) return;

    const uint4* h128 = (const uint4*)hs;
    int start = rowptr[node], end = rowptr[node + 1];

    float a[8];
    {
        uint4 v = h128[(size_t)node * WPN + fl];  // self loop h'[c]
        a[0] = bflo(v.x); a[1] = bfhi(v.x); a[2] = bflo(v.y); a[3] = bfhi(v.y);
        a[4] = bflo(v.z); a[5] = bfhi(v.z); a[6] = bflo(v.w); a[7] = bfhi(v.w);
    }

    int nfull = (end - start) >> 3;
    int i = start;
    int r[8], r2[8];
    if (nfull > 0) {
#pragma unroll
        for (int j = 0; j < 8; j++) r[j] = srcidx[i + j];
    }
    for (int b = 0; b < nfull; b++) {
        uint4 u[8];
#pragma unroll
        for (int j = 0; j < 8; j++) u[j] = h128[(size_t)r[j] * WPN + fl];
        if (b + 1 < nfull) {
#pragma unroll
            for (int j = 0; j < 8; j++) r2[j] = srcidx[i + 8 + j];
        }
#pragma unroll
        for (int j = 0; j < 8; j++) {
            a[0] += bflo(u[j].x); a[1] += bfhi(u[j].x);
            a[2] += bflo(u[j].y); a[3] += bfhi(u[j].y);
            a[4] += bflo(u[j].z); a[5] += bfhi(u[j].z);
            a[6] += bflo(u[j].w); a[7] += bfhi(u[j].w);
        }
#pragma unroll
        for (int j = 0; j < 8; j++) r[j] = r2[j];
        i += 8;
    }
    if (i + 4 <= end) {
        int rr[4];
#pragma unroll
        for (int j = 0; j < 4; j++) rr[j] = srcidx[i + j];
        uint4 u[4];
#pragma unroll
        for (int j = 0; j < 4; j++) u[j] = h128[(size_t)rr[j] * WPN + fl];
#pragma unroll
        for (int j = 0; j < 4; j++) {
            a[0] += bflo(u[j].x); a[1] += bfhi(u[j].x);
            a[2] += bflo(u[j].y); a[3] += bfhi(u[j].y);
            a[4] += bflo(u[j].z); a[5] += bfhi(u[j].z);
            a[6] += bflo(u[j].w); a[7] += bfhi(u[j].w);
        }
        i += 4;
    }
    for (; i < end; ++i) {
        uint4 u = h128[(size_t)srcidx[i] * WPN + fl];
        a[0] += bflo(u.x); a[1] += bfhi(u.x);
        a[2] += bflo(u.y); a[3] += bfhi(u.y);
        a[4] += bflo(u.z); a[5] += bfhi(u.z);
        a[6] += bflo(u.w); a[7] += bfhi(u.w);
    }

    float dv = dinv[node];
    float4 bv0 = ((const float4*)bias)[2 * fl];
    float4 bv1 = ((const float4*)bias)[2 * fl + 1];
    float o[8];
    o[0] = dv * a[0] + bv0.x; o[1] = dv * a[1] + bv0.y;
    o[2] = dv * a[2] + bv0.z; o[3] = dv * a[3] + bv0.w;
    o[4] = dv * a[4] + bv1.x; o[5] = dv * a[5] + bv1.y;
    o[6] = dv * a[6] + bv1.z; o[7] = dv * a[7] + bv1.w;
    if (RELU) {
#pragma unroll
        for (int j = 0; j < 8; j++) o[j] = fmaxf(o[j], 0.f);
    }
    if (OUT_BF16) {
        uint4 w;
        w.x = (unsigned)f2bf(o[0]) | ((unsigned)f2bf(o[1]) << 16);
        w.y = (unsigned)f2bf(o[2]) | ((unsigned)f2bf(o[3]) << 16);
        w.z = (unsigned)f2bf(o[4]) | ((unsigned)f2bf(o[5]) << 16);
        w.w = (unsigned)f2bf(o[6]) | ((unsigned)f2bf(o[7]) << 16);
        ((uint4*)outv)[tid] = w;
    } else {
        ((float4*)outv)[2 * tid] = make_float4(o[0], o[1], o[2], o[3]);
        ((float4*)outv)[2 * tid + 1] = make_float4(o[4], o[5], o[6], o[7]);
    }
}

extern "C" void kernel_launch(void* const* d_in, const int* in_sizes, int n_in,
                              void* d_out, int out_size, void* d_ws, size_t ws_size,
                              hipStream_t stream) {
    const float* x  = (const float*)d_in[0];
    const int*   ei = (const int*)d_in[1];
    const float* W1 = (const float*)d_in[2];
    const float* b1 = (const float*)d_in[3];
    const float* W2 = (const float*)d_in[4];
    const float* b2 = (const float*)d_in[5];

    const int N = in_sizes[0] / 128;
    const int E = in_sizes[1] / 2;
    const int* rows = ei;
    const int* cols = ei + E;

    const int nbuckets = (N + BN - 1) / BN;          // 196 for N=100k (<=256)
    const int nblocksA = (E + CHUNK - 1) / CHUNK;    // 196 for E=1.6M (<=256)

    char* ws = (char*)d_ws;
    size_t off = 0;
    auto alloc = [&](size_t bytes) -> void* {
        void* p = ws + off;
        off = (off + bytes + 1023) & ~(size_t)1023;
        return p;
    };
    unsigned* hist       = (unsigned*)alloc((size_t)nbuckets * nblocksA * 4);
    unsigned* totals     = (unsigned*)alloc(256 * 4);
    unsigned* bucketbase = (unsigned*)alloc((size_t)(nbuckets + 1) * 4);
    uint2*    binned     = (uint2*)alloc((size_t)E * 8);
    int*      rowptr     = (int*)alloc((size_t)(N + 1) * 4);
    float*    dinv       = (float*)alloc((size_t)N * 4);
    int*      srcidx     = (int*)alloc((size_t)E * 4);
    u16*      WT1        = (u16*)alloc((size_t)128 * 128 * 2);
    u16*      WT2        = (u16*)alloc((size_t)64 * 128 * 2);
    u16*      h1s        = (u16*)alloc((size_t)N * 128 * 2);
    u16*      h1b        = (u16*)alloc((size_t)N * 128 * 2);
    u16*      h2s        = h1s;

    // CSR build (binned two-level counting sort)
    hist_kernel<<<nblocksA, 256, 0, stream>>>(cols, hist, E, nbuckets);
    scanA1_kernel<<<nbuckets, 256, 0, stream>>>(hist, totals, nblocksA, nbuckets);
    scanA2_kernel<<<1, 256, 0, stream>>>(totals, bucketbase, nbuckets);
    scatterA_kernel<<<nblocksA, 256, 0, stream>>>(rows, cols, hist, bucketbase, binned, E, nbuckets);
    binB_kernel<<<nbuckets, 256, 0, stream>>>(binned, bucketbase, rowptr, dinv, srcidx, N, E, nbuckets);

    prep_wt<<<96, 256, 0, stream>>>(W1, W2, WT1, WT2);

    // layer 1
    gemm_mfma<128, false><<<(N + 63) / 64, 256, 0, stream>>>(x, WT1, dinv, h1s, N);
    aggregate<128, true, true><<<(N * 16 + 255) / 256, 256, 0, stream>>>(
        rowptr, srcidx, h1s, dinv, b1, h1b, N);

    // layer 2
    gemm_mfma<64, true><<<(N + 63) / 64, 256, 0, stream>>>(h1b, WT2, dinv, h2s, N);
    aggregate<64, false, false><<<(N * 8 + 255) / 256, 256, 0, stream>>>(
        rowptr, srcidx, h2s, dinv, b2, d_out, N);
}

// Round 9
// 273.079 us; speedup vs baseline: 8.2888x; 1.0471x over previous
//
#include <hip/hip_runtime.h>
#include <hip/hip_bf16.h>

typedef unsigned short u16;
typedef short bf16x8 __attribute__((ext_vector_type(8)));
typedef float f32x4 __attribute__((ext_vector_type(4)));

__device__ __forceinline__ float bflo(unsigned u) { return __uint_as_float(u << 16); }
__device__ __forceinline__ float bfhi(unsigned u) { return __uint_as_float(u & 0xffff0000u); }
__device__ __forceinline__ u16 f2bf(float f) {
    unsigned u = __float_as_uint(f);
    return (u16)((u + 0x7fffu + ((u >> 16) & 1u)) >> 16);  // RNE
}

#define CHUNK 8192     // edges per block in pass A
#define BN 512         // nodes per bucket (bucket = c >> 9)

// ---- pass A1: per-block bucket histogram (hist layout: [blk][bucket])
//      + fused W->bf16 transpose in trailing blocks ----
__global__ __launch_bounds__(256) void hist_prep_kernel(const int* __restrict__ cols,
                                                        unsigned* __restrict__ hist,
                                                        int E, int nbuckets, int nblocksA,
                                                        const float* __restrict__ W1,
                                                        const float* __restrict__ W2,
                                                        u16* __restrict__ WT1,
                                                        u16* __restrict__ WT2) {
    int blk = blockIdx.x;
    if (blk >= nblocksA) {
        int t = (blk - nblocksA) * 256 + threadIdx.x;
        if (t < 128 * 128) {
            int n = t >> 7, k = t & 127;
            WT1[n * 128 + k] = f2bf(W1[k * 128 + n]);
        } else if (t < 128 * 128 + 64 * 128) {
            int i = t - 128 * 128;
            int n = i >> 7, k = i & 127;
            WT2[n * 128 + k] = f2bf(W2[k * 64 + n]);
        }
        return;
    }
    __shared__ unsigned h[256];
    int t = threadIdx.x;
    h[t] = 0;
    __syncthreads();
    int base = blk * CHUNK;
#pragma unroll
    for (int j = 0; j < CHUNK / 256; j++) {
        int i = base + j * 256 + t;
        if (i < E) atomicAdd(&h[((unsigned)cols[i]) >> 9], 1u);
    }
    __syncthreads();
    if (t < nbuckets) hist[blk * nbuckets + t] = h[t];
}

// ---- pass A2a: per-bucket prefix over blocks (one WG per bucket) ----
__global__ __launch_bounds__(256) void scanA1_kernel(unsigned* __restrict__ hist,
                                                     unsigned* __restrict__ totals,
                                                     int nblocksA, int nbuckets) {
    __shared__ unsigned s[256];
    int t = threadIdx.x, b = blockIdx.x;
    unsigned val = (t < nblocksA) ? hist[t * nbuckets + b] : 0u;
    s[t] = val;
    __syncthreads();
    for (int off = 1; off < 256; off <<= 1) {
        unsigned v = (t >= off) ? s[t - off] : 0u;
        __syncthreads();
        s[t] += v;
        __syncthreads();
    }
    if (t < nblocksA) hist[t * nbuckets + b] = s[t] - val;  // exclusive
    if (t == 255) totals[b] = s[255];
}

// ---- pass A2b: bucket bases (single WG) ----
__global__ __launch_bounds__(256) void scanA2_kernel(const unsigned* __restrict__ totals,
                                                     unsigned* __restrict__ bucketbase,
                                                     int nbuckets) {
    __shared__ unsigned s[256];
    int t = threadIdx.x;
    unsigned val = (t < nbuckets) ? totals[t] : 0u;
    s[t] = val;
    __syncthreads();
    for (int off = 1; off < 256; off <<= 1) {
        unsigned v = (t >= off) ? s[t - off] : 0u;
        __syncthreads();
        s[t] += v;
        __syncthreads();
    }
    unsigned ex = s[t] - val;
    if (t < nbuckets) bucketbase[t] = ex;
    if (t == nbuckets - 1) bucketbase[nbuckets] = ex + val;  // == E
}

// ---- pass A3: LDS-staged scatter -> coalesced bucket-group writes ----
__global__ __launch_bounds__(256) void scatterA_kernel(const int* __restrict__ rows,
                                                       const int* __restrict__ cols,
                                                       const unsigned* __restrict__ hist,
                                                       const unsigned* __restrict__ bucketbase,
                                                       uint2* __restrict__ binned,
                                                       int E, int nbuckets) {
    __shared__ uint2 sp[CHUNK];        // 64 KB staging
    __shared__ unsigned lstart[256];   // LDS group starts
    __shared__ unsigned lcur[256];     // cursors
    __shared__ unsigned gbase[256];    // global base per bucket for this block
    int t = threadIdx.x, blk = blockIdx.x;
    int base = blk * CHUNK;
    int cnt = min(CHUNK, E - base);

    lcur[t] = 0;
    __syncthreads();
    for (int i = t; i < cnt; i += 256)
        atomicAdd(&lcur[((unsigned)cols[base + i]) >> 9], 1u);
    __syncthreads();
    unsigned val = lcur[t];
    lstart[t] = val;
    __syncthreads();
    for (int off = 1; off < 256; off <<= 1) {
        unsigned v = (t >= off) ? lstart[t - off] : 0u;
        __syncthreads();
        lstart[t] += v;
        __syncthreads();
    }
    unsigned ex = lstart[t] - val;
    __syncthreads();
    lstart[t] = ex;
    lcur[t] = ex;
    if (t < nbuckets) gbase[t] = bucketbase[t] + hist[blk * nbuckets + t];
    __syncthreads();
    for (int i = t; i < cnt; i += 256) {
        unsigned c = (unsigned)cols[base + i];
        unsigned r = (unsigned)rows[base + i];
        unsigned pos = atomicAdd(&lcur[c >> 9], 1u);
        sp[pos] = make_uint2(r, c);
    }
    __syncthreads();
    for (int i = t; i < cnt; i += 256) {
        uint2 u = sp[i];
        unsigned g = u.y >> 9;
        binned[gbase[g] + (unsigned)i - lstart[g]] = u;
    }
}

// ---- pass B: per bucket — local count/scan -> rowptr, dinv, srcidx ----
__global__ __launch_bounds__(256) void binB_kernel(const uint2* __restrict__ binned,
                                                   const unsigned* __restrict__ bucketbase,
                                                   int* __restrict__ rowptr,
                                                   float* __restrict__ dinv,
                                                   int* __restrict__ srcidx,
                                                   int N, int E, int nbuckets) {
    __shared__ unsigned cnt[BN + 1];
    __shared__ unsigned sc[BN + 1];
    __shared__ unsigned ps[256];
    int t = threadIdx.x, b = blockIdx.x;
    int lo = b << 9;
    int nn = min(BN, N - lo);
    unsigned s = bucketbase[b], e = bucketbase[b + 1];

    cnt[t] = 0;
    cnt[t + 256] = 0;
    if (t == 0) cnt[BN] = 0;
    __syncthreads();
    for (unsigned i = s + t; i < e; i += 256)
        atomicAdd(&cnt[binned[i].y - lo], 1u);
    __syncthreads();

    unsigned a0 = cnt[2 * t], a1 = cnt[2 * t + 1];
    ps[t] = a0 + a1;
    __syncthreads();
    unsigned val = ps[t];
    for (int off = 1; off < 256; off <<= 1) {
        unsigned v = (t >= off) ? ps[t - off] : 0u;
        __syncthreads();
        ps[t] += v;
        __syncthreads();
    }
    unsigned ex = ps[t] - val;
    sc[2 * t] = ex;
    sc[2 * t + 1] = ex + a0;
    if (t == 255) sc[BN] = ex + val;
    __syncthreads();

    for (int n = t; n < nn; n += 256) {
        unsigned rp = s + sc[n];
        rowptr[lo + n] = (int)rp;
        dinv[lo + n] = rsqrtf((float)(sc[n + 1] - sc[n]) + 1.0f);
        cnt[n] = rp;
    }
    if (b == nbuckets - 1 && t == 0) rowptr[N] = E;
    __syncthreads();

    for (unsigned i = s + t; i < e; i += 256) {
        uint2 u = binned[i];
        unsigned slot = atomicAdd(&cnt[u.y - lo], 1u);
        srcidx[slot] = (int)u.x;
    }
}

// ---- MFMA bf16 GEMM: OutH[i,:] = bf16((X[i,:] @ W) * dinv[i]) ----
template <int NOUT, bool IN_BF16>
__global__ __launch_bounds__(256) void gemm_mfma(const void* __restrict__ Xv,
                                                 const u16* __restrict__ WT,  // [NOUT][128] bf16
                                                 const float* __restrict__ dinv,
                                                 u16* __restrict__ OutH, int nrows) {
    constexpr int LDK = 136;
    __shared__ u16 sX[64 * LDK];
    __shared__ u16 sW[NOUT * LDK];

    const int t = threadIdx.x;
    const int wv = t >> 6, lane = t & 63;
    const int m = lane & 15, q = lane >> 4;
    const int row0 = blockIdx.x * 64;

    for (int idx = t; idx < NOUT * 16; idx += 256) {
        int n = idx >> 4, c = idx & 15;
        *((uint4*)&sW[n * LDK + c * 8]) = ((const uint4*)WT)[idx];
    }
    if (IN_BF16) {
        const u16* X = (const u16*)Xv;
        for (int idx = t; idx < 64 * 16; idx += 256) {
            int r = idx >> 4, c = idx & 15;
            int gr = row0 + r;
            uint4 v = make_uint4(0u, 0u, 0u, 0u);
            if (gr < nrows) v = ((const uint4*)X)[(size_t)gr * 16 + c];
            *((uint4*)&sX[r * LDK + c * 8]) = v;
        }
    } else {
        const float* X = (const float*)Xv;
        for (int idx = t; idx < 64 * 32; idx += 256) {
            int r = idx >> 5, c = idx & 31;
            int gr = row0 + r;
            float4 v = make_float4(0.f, 0.f, 0.f, 0.f);
            if (gr < nrows) v = ((const float4*)X)[(size_t)gr * 32 + c];
            uint2 o;
            o.x = (unsigned)f2bf(v.x) | ((unsigned)f2bf(v.y) << 16);
            o.y = (unsigned)f2bf(v.z) | ((unsigned)f2bf(v.w) << 16);
            *((uint2*)&sX[r * LDK + c * 4]) = o;
        }
    }
    __syncthreads();

    f32x4 acc[NOUT / 16];
#pragma unroll
    for (int i = 0; i < NOUT / 16; i++) acc[i] = (f32x4){0.f, 0.f, 0.f, 0.f};

#pragma unroll
    for (int ks = 0; ks < 4; ks++) {
        const int k0 = ks * 32 + q * 8;
        bf16x8 a = *((const bf16x8*)&sX[(wv * 16 + m) * LDK + k0]);
#pragma unroll
        for (int nt = 0; nt < NOUT / 16; nt++) {
            bf16x8 b = *((const bf16x8*)&sW[(nt * 16 + m) * LDK + k0]);
            acc[nt] = __builtin_amdgcn_mfma_f32_16x16x32_bf16(a, b, acc[nt], 0, 0, 0);
        }
    }

#pragma unroll
    for (int r = 0; r < 4; r++) {
        int gi = row0 + wv * 16 + q * 4 + r;
        if (gi < nrows) {
            float dv = dinv[gi];
#pragma unroll
            for (int nt = 0; nt < NOUT / 16; nt++) {
                OutH[(size_t)gi * NOUT + nt * 16 + m] = f2bf(acc[nt][r] * dv);
            }
        }
    }
}

// ---- fused layer-1 aggregate + relu + layer-2 GEMM ----
// Block = 256 threads = 16 nodes. Phase 1: aggregate h1s rows (WPN=16 lanes/node,
// uint4 each) -> out1 = relu(dinv*(sum+self)+b1), rounded to bf16 into LDS tile
// sO[16][128]. Phase 2: wave w computes h2s tile [16 nodes][w*16..w*16+16) via
// 4 MFMAs against staged W2^T, scaled by dinv[row].
__global__ __launch_bounds__(256) void agg1_gemm2(const int* __restrict__ rowptr,
                                                  const int* __restrict__ srcidx,
                                                  const u16* __restrict__ hs,     // h1s [N][128] bf16
                                                  const float* __restrict__ dinv,
                                                  const float* __restrict__ bias, // b1
                                                  const u16* __restrict__ WT2,    // [64][128] bf16
                                                  u16* __restrict__ h2s, int N) {
    constexpr int WPN = 16;   // lanes per node (128 feats / 8 per lane)
    constexpr int LDK = 136;
    __shared__ u16 sO[16 * LDK];
    __shared__ u16 sW[64 * LDK];

    const int t = threadIdx.x;
    const int node_l = t / WPN;         // 0..15
    const int fl = t % WPN;
    const int node = blockIdx.x * 16 + node_l;
    const bool valid = node < N;

    // stage W2^T [64][128]
    for (int idx = t; idx < 64 * 16; idx += 256) {
        int n = idx >> 4, c = idx & 15;
        *((uint4*)&sW[n * LDK + c * 8]) = ((const uint4*)WT2)[idx];
    }

    // ---- phase 1: aggregation ----
    const uint4* h128 = (const uint4*)hs;
    float a[8];
#pragma unroll
    for (int j = 0; j < 8; j++) a[j] = 0.f;

    if (valid) {
        int start = rowptr[node], end = rowptr[node + 1];
        {
            uint4 v = h128[(size_t)node * WPN + fl];  // self loop
            a[0] = bflo(v.x); a[1] = bfhi(v.x); a[2] = bflo(v.y); a[3] = bfhi(v.y);
            a[4] = bflo(v.z); a[5] = bfhi(v.z); a[6] = bflo(v.w); a[7] = bfhi(v.w);
        }
        int nfull = (end - start) >> 3;
        int i = start;
        int r[8], r2[8];
        if (nfull > 0) {
#pragma unroll
            for (int j = 0; j < 8; j++) r[j] = srcidx[i + j];
        }
        for (int b = 0; b < nfull; b++) {
            uint4 u[8];
#pragma unroll
            for (int j = 0; j < 8; j++) u[j] = h128[(size_t)r[j] * WPN + fl];
            if (b + 1 < nfull) {
#pragma unroll
                for (int j = 0; j < 8; j++) r2[j] = srcidx[i + 8 + j];
            }
#pragma unroll
            for (int j = 0; j < 8; j++) {
                a[0] += bflo(u[j].x); a[1] += bfhi(u[j].x);
                a[2] += bflo(u[j].y); a[3] += bfhi(u[j].y);
                a[4] += bflo(u[j].z); a[5] += bfhi(u[j].z);
                a[6] += bflo(u[j].w); a[7] += bfhi(u[j].w);
            }
#pragma unroll
            for (int j = 0; j < 8; j++) r[j] = r2[j];
            i += 8;
        }
        if (i + 4 <= end) {
            int rr[4];
#pragma unroll
            for (int j = 0; j < 4; j++) rr[j] = srcidx[i + j];
            uint4 u[4];
#pragma unroll
            for (int j = 0; j < 4; j++) u[j] = h128[(size_t)rr[j] * WPN + fl];
#pragma unroll
            for (int j = 0; j < 4; j++) {
                a[0] += bflo(u[j].x); a[1] += bfhi(u[j].x);
                a[2] += bflo(u[j].y); a[3] += bfhi(u[j].y);
                a[4] += bflo(u[j].z); a[5] += bfhi(u[j].z);
                a[6] += bflo(u[j].w); a[7] += bfhi(u[j].w);
            }
            i += 4;
        }
        for (; i < end; ++i) {
            uint4 u = h128[(size_t)srcidx[i] * WPN + fl];
            a[0] += bflo(u.x); a[1] += bfhi(u.x);
            a[2] += bflo(u.y); a[3] += bfhi(u.y);
            a[4] += bflo(u.z); a[5] += bfhi(u.z);
            a[6] += bflo(u.w); a[7] += bfhi(u.w);
        }
    }

    float dv = valid ? dinv[node] : 0.f;
    float4 bv0 = ((const float4*)bias)[2 * fl];
    float4 bv1 = ((const float4*)bias)[2 * fl + 1];
    float o[8];
    o[0] = fmaxf(dv * a[0] + bv0.x, 0.f); o[1] = fmaxf(dv * a[1] + bv0.y, 0.f);
    o[2] = fmaxf(dv * a[2] + bv0.z, 0.f); o[3] = fmaxf(dv * a[3] + bv0.w, 0.f);
    o[4] = fmaxf(dv * a[4] + bv1.x, 0.f); o[5] = fmaxf(dv * a[5] + bv1.y, 0.f);
    o[6] = fmaxf(dv * a[6] + bv1.z, 0.f); o[7] = fmaxf(dv * a[7] + bv1.w, 0.f);
    uint4 w;
    w.x = (unsigned)f2bf(o[0]) | ((unsigned)f2bf(o[1]) << 16);
    w.y = (unsigned)f2bf(o[2]) | ((unsigned)f2bf(o[3]) << 16);
    w.z = (unsigned)f2bf(o[4]) | ((unsigned)f2bf(o[5]) << 16);
    w.w = (unsigned)f2bf(o[6]) | ((unsigned)f2bf(o[7]) << 16);
    *((uint4*)&sO[node_l * LDK + fl * 8]) = w;
    __syncthreads();

    // ---- phase 2: 16x64 GEMM vs W2 (wave wv -> feature tile wv*16) ----
    const int wv = t >> 6, lane = t & 63;
    const int m = lane & 15, q = lane >> 4;
    f32x4 acc = (f32x4){0.f, 0.f, 0.f, 0.f};
#pragma unroll
    for (int ks = 0; ks < 4; ks++) {
        const int k0 = ks * 32 + q * 8;
        bf16x8 af = *((const bf16x8*)&sO[m * LDK + k0]);
        bf16x8 bf = *((const bf16x8*)&sW[(wv * 16 + m) * LDK + k0]);
        acc = __builtin_amdgcn_mfma_f32_16x16x32_bf16(af, bf, acc, 0, 0, 0);
    }
#pragma unroll
    for (int r = 0; r < 4; r++) {
        int gi = blockIdx.x * 16 + q * 4 + r;
        if (gi < N) {
            float dvv = dinv[gi];
            h2s[(size_t)gi * 64 + wv * 16 + m] = f2bf(acc[r] * dvv);
        }
    }
}

// ---- aggregate+finalize (layer 2): out[c] = dinv[c]*(Σ h2s[r] + h2s[c]) + b2 ----
template <int NH, bool RELU, bool OUT_BF16>
__global__ __launch_bounds__(256) void aggregate(const int* __restrict__ rowptr,
                                                 const int* __restrict__ srcidx,
                                                 const u16* __restrict__ hs,
                                                 const float* __restrict__ dinv,
                                                 const float* __restrict__ bias,
                                                 void* __restrict__ outv, int N) {
    constexpr int WPN = NH / 8;
    int tid = blockIdx.x * 256 + threadIdx.x;
    int node = tid / WPN;
    int fl = tid % WPN;
    if (node >= N) return;

    const uint4* h128 = (const uint4*)hs;
    int start = rowptr[node], end = rowptr[node + 1];

    float a[8];
    {
        uint4 v = h128[(size_t)node * WPN + fl];
        a[0] = bflo(v.x); a[1] = bfhi(v.x); a[2] = bflo(v.y); a[3] = bfhi(v.y);
        a[4] = bflo(v.z); a[5] = bfhi(v.z); a[6] = bflo(v.w); a[7] = bfhi(v.w);
    }

    int nfull = (end - start) >> 3;
    int i = start;
    int r[8], r2[8];
    if (nfull > 0) {
#pragma unroll
        for (int j = 0; j < 8; j++) r[j] = srcidx[i + j];
    }
    for (int b = 0; b < nfull; b++) {
        uint4 u[8];
#pragma unroll
        for (int j = 0; j < 8; j++) u[j] = h128[(size_t)r[j] * WPN + fl];
        if (b + 1 < nfull) {
#pragma unroll
            for (int j = 0; j < 8; j++) r2[j] = srcidx[i + 8 + j];
        }
#pragma unroll
        for (int j = 0; j < 8; j++) {
            a[0] += bflo(u[j].x); a[1] += bfhi(u[j].x);
            a[2] += bflo(u[j].y); a[3] += bfhi(u[j].y);
            a[4] += bflo(u[j].z); a[5] += bfhi(u[j].z);
            a[6] += bflo(u[j].w); a[7] += bfhi(u[j].w);
        }
#pragma unroll
        for (int j = 0; j < 8; j++) r[j] = r2[j];
        i += 8;
    }
    if (i + 4 <= end) {
        int rr[4];
#pragma unroll
        for (int j = 0; j < 4; j++) rr[j] = srcidx[i + j];
        uint4 u[4];
#pragma unroll
        for (int j = 0; j < 4; j++) u[j] = h128[(size_t)rr[j] * WPN + fl];
#pragma unroll
        for (int j = 0; j < 4; j++) {
            a[0] += bflo(u[j].x); a[1] += bfhi(u[j].x);
            a[2] += bflo(u[j].y); a[3] += bfhi(u[j].y);
            a[4] += bflo(u[j].z); a[5] += bfhi(u[j].z);
            a[6] += bflo(u[j].w); a[7] += bfhi(u[j].w);
        }
        i += 4;
    }
    for (; i < end; ++i) {
        uint4 u = h128[(size_t)srcidx[i] * WPN + fl];
        a[0] += bflo(u.x); a[1] += bfhi(u.x);
        a[2] += bflo(u.y); a[3] += bfhi(u.y);
        a[4] += bflo(u.z); a[5] += bfhi(u.z);
        a[6] += bflo(u.w); a[7] += bfhi(u.w);
    }

    float dv = dinv[node];
    float4 bv0 = ((const float4*)bias)[2 * fl];
    float4 bv1 = ((const float4*)bias)[2 * fl + 1];
    float o[8];
    o[0] = dv * a[0] + bv0.x; o[1] = dv * a[1] + bv0.y;
    o[2] = dv * a[2] + bv0.z; o[3] = dv * a[3] + bv0.w;
    o[4] = dv * a[4] + bv1.x; o[5] = dv * a[5] + bv1.y;
    o[6] = dv * a[6] + bv1.z; o[7] = dv * a[7] + bv1.w;
    if (RELU) {
#pragma unroll
        for (int j = 0; j < 8; j++) o[j] = fmaxf(o[j], 0.f);
    }
    if (OUT_BF16) {
        uint4 w;
        w.x = (unsigned)f2bf(o[0]) | ((unsigned)f2bf(o[1]) << 16);
        w.y = (unsigned)f2bf(o[2]) | ((unsigned)f2bf(o[3]) << 16);
        w.z = (unsigned)f2bf(o[4]) | ((unsigned)f2bf(o[5]) << 16);
        w.w = (unsigned)f2bf(o[6]) | ((unsigned)f2bf(o[7]) << 16);
        ((uint4*)outv)[tid] = w;
    } else {
        ((float4*)outv)[2 * tid] = make_float4(o[0], o[1], o[2], o[3]);
        ((float4*)outv)[2 * tid + 1] = make_float4(o[4], o[5], o[6], o[7]);
    }
}

extern "C" void kernel_launch(void* const* d_in, const int* in_sizes, int n_in,
                              void* d_out, int out_size, void* d_ws, size_t ws_size,
                              hipStream_t stream) {
    const float* x  = (const float*)d_in[0];
    const int*   ei = (const int*)d_in[1];
    const float* W1 = (const float*)d_in[2];
    const float* b1 = (const float*)d_in[3];
    const float* W2 = (const float*)d_in[4];
    const float* b2 = (const float*)d_in[5];

    const int N = in_sizes[0] / 128;
    const int E = in_sizes[1] / 2;
    const int* rows = ei;
    const int* cols = ei + E;

    const int nbuckets = (N + BN - 1) / BN;          // 196 for N=100k (<=256)
    const int nblocksA = (E + CHUNK - 1) / CHUNK;    // 196 for E=1.6M (<=256)

    char* ws = (char*)d_ws;
    size_t off = 0;
    auto alloc = [&](size_t bytes) -> void* {
        void* p = ws + off;
        off = (off + bytes + 1023) & ~(size_t)1023;
        return p;
    };
    unsigned* hist       = (unsigned*)alloc((size_t)nbuckets * nblocksA * 4);
    unsigned* totals     = (unsigned*)alloc(256 * 4);
    unsigned* bucketbase = (unsigned*)alloc((size_t)(nbuckets + 1) * 4);
    uint2*    binned     = (uint2*)alloc((size_t)E * 8);
    int*      rowptr     = (int*)alloc((size_t)(N + 1) * 4);
    float*    dinv       = (float*)alloc((size_t)N * 4);
    int*      srcidx     = (int*)alloc((size_t)E * 4);
    u16*      WT1        = (u16*)alloc((size_t)128 * 128 * 2);
    u16*      WT2        = (u16*)alloc((size_t)64 * 128 * 2);
    u16*      h1s        = (u16*)alloc((size_t)N * 128 * 2);
    u16*      h2s        = (u16*)alloc((size_t)N * 64 * 2);

    // CSR build (binned two-level counting sort) + fused weight prep
    hist_prep_kernel<<<nblocksA + 96, 256, 0, stream>>>(cols, hist, E, nbuckets, nblocksA,
                                                        W1, W2, WT1, WT2);
    scanA1_kernel<<<nbuckets, 256, 0, stream>>>(hist, totals, nblocksA, nbuckets);
    scanA2_kernel<<<1, 256, 0, stream>>>(totals, bucketbase, nbuckets);
    scatterA_kernel<<<nblocksA, 256, 0, stream>>>(rows, cols, hist, bucketbase, binned, E, nbuckets);
    binB_kernel<<<nbuckets, 256, 0, stream>>>(binned, bucketbase, rowptr, dinv, srcidx, N, E, nbuckets);

    // layer 1 GEMM
    gemm_mfma<128, false><<<(N + 63) / 64, 256, 0, stream>>>(x, WT1, dinv, h1s, N);

    // fused: layer-1 aggregate + relu + layer-2 GEMM
    agg1_gemm2<<<(N + 15) / 16, 256, 0, stream>>>(rowptr, srcidx, h1s, dinv, b1, WT2, h2s, N);

    // layer-2 aggregate + bias -> fp32 out
    aggregate<64, false, false><<<(N * 8 + 255) / 256, 256, 0, stream>>>(
        rowptr, srcidx, h2s, dinv, b2, d_out, N);
}